// Round 8
// baseline (110.954 us; speedup 1.0000x reference)
//
#include <hip/hip_runtime.h>
#include <hip/hip_bf16.h>

#define NEG_SLOPE 0.2f
#define CAP 5120          // per-bucket capacity (avg 4096, ~16-sigma margin)
#define CHUNK 4096        // edges per workgroup in bfill path
#define LOG2E 1.4426950408889634f

typedef __attribute__((ext_vector_type(8))) short short8v;
typedef __attribute__((ext_vector_type(4))) short short4v;
typedef __attribute__((ext_vector_type(4))) float f32x4;

__device__ __forceinline__ short f2bf(float f) {
  __hip_bfloat16 b = __float2bfloat16(f);  // RNE
  return *reinterpret_cast<short*>(&b);
}
__device__ __forceinline__ float bf2f(short s) {
  return __uint_as_float(((unsigned)(unsigned short)s) << 16);
}

// K0: zero bucket cursors (must precede k_tb's bfill blocks).
__global__ __launch_bounds__(256) void k_zero(int* __restrict__ bcur, int nbk) {
  if (threadIdx.x < nbk) bcur[threadIdx.x] = 0;
}

// K1 fused: blocks [0, nbf) do bucketed edge fill; blocks [nbf, ...) do the
// MFMA transform (reads Wl/Wr/bl/br directly, no weight prepass needed).
__global__ __launch_bounds__(256) void k_tb(
    const float* __restrict__ x, const float* __restrict__ Wl,
    const float* __restrict__ Wr, const float* __restrict__ bl,
    const float* __restrict__ br, const int* __restrict__ eidx,
    int* __restrict__ bcur, unsigned* __restrict__ pk,
    short* __restrict__ xlb, float* __restrict__ xr, int nN, int E_,
    int nbf) {
  __shared__ int hist[256];
  __shared__ int base[256];
  const int t = threadIdx.x;

  if (blockIdx.x < nbf) {
    // ---------------- bfill path ----------------
    hist[t] = 0;
    __syncthreads();
    const int e0 = blockIdx.x * CHUNK + t * 16;
    unsigned mypk[16];
    int myrank[16];
    const bool valid = (e0 < E_);  // E_ % 16 == 0 -> all-or-nothing per thread
    if (valid) {
      const int4* ps = (const int4*)(eidx + e0);
      const int4* pd = (const int4*)(eidx + E_ + e0);
#pragma unroll
      for (int j = 0; j < 4; ++j) {
        int4 sv = ps[j];
        int4 dv = pd[j];
        int ss[4] = {sv.x, sv.y, sv.z, sv.w};
        int dd[4] = {dv.x, dv.y, dv.z, dv.w};
#pragma unroll
        for (int q = 0; q < 4; ++q) {
          unsigned p = ((unsigned)dd[q] << 16) | (unsigned)ss[q];
          mypk[j * 4 + q] = p;
          myrank[j * 4 + q] = atomicAdd(&hist[dd[q] >> 8], 1);
        }
      }
    }
    __syncthreads();
    base[t] = hist[t] ? atomicAdd(&bcur[t], hist[t]) : 0;
    __syncthreads();
    if (valid) {
#pragma unroll
      for (int j = 0; j < 16; ++j) {
        int b = mypk[j] >> 24;  // dst>>8
        unsigned idx = (unsigned)(base[b] + myrank[j]);
        if (idx < CAP) pk[(unsigned)b * CAP + idx] = mypk[j];
      }
    }
    return;
  }

  // ---------------- transform path ----------------
  const int wave = ((blockIdx.x - nbf) * 256 + t) >> 6;
  const int lane = t & 63;
  const int ntile = wave >> 3;   // 8 ch-tiles per node-tile
  const int ctile = wave & 7;
  const int n0 = ntile * 16;
  if (n0 >= nN) return;
  const int r = lane & 15;
  const int kb = lane >> 4;
  const int nrow = min(n0 + r, nN - 1);
  const int ch = ctile * 16 + r;
  const float* ap = x + (size_t)nrow * 128 + kb * 8;
  const float* wrow = ((ch < 64) ? (Wl + (size_t)ch * 128)
                                 : (Wr + (size_t)(ch - 64) * 128)) + kb * 8;
  f32x4 acc = {0.f, 0.f, 0.f, 0.f};
#pragma unroll
  for (int kk = 0; kk < 4; ++kk) {
    float4 a0 = *(const float4*)(ap + kk * 32);
    float4 a1 = *(const float4*)(ap + kk * 32 + 4);
    float4 w0 = *(const float4*)(wrow + kk * 32);
    float4 w1 = *(const float4*)(wrow + kk * 32 + 4);
    short8v a, b;
    a[0] = f2bf(a0.x); a[1] = f2bf(a0.y); a[2] = f2bf(a0.z); a[3] = f2bf(a0.w);
    a[4] = f2bf(a1.x); a[5] = f2bf(a1.y); a[6] = f2bf(a1.z); a[7] = f2bf(a1.w);
    b[0] = f2bf(w0.x); b[1] = f2bf(w0.y); b[2] = f2bf(w0.z); b[3] = f2bf(w0.w);
    b[4] = f2bf(w1.x); b[5] = f2bf(w1.y); b[6] = f2bf(w1.z); b[7] = f2bf(w1.w);
    acc = __builtin_amdgcn_mfma_f32_16x16x32_bf16(a, b, acc, 0, 0, 0);
  }
  const float bv = (ch < 64) ? bl[ch] : br[ch - 64];
#pragma unroll
  for (int i = 0; i < 4; ++i) {
    int node = n0 + kb * 4 + i;
    if (node < nN) {
      float v = acc[i] + bv;
      if (ch < 64) xlb[(size_t)node * 64 + ch] = f2bf(v);
      else         xr[(size_t)node * 64 + (ch - 64)] = v;
    }
  }
}

// K2: per-bucket node-level finalize. One WG per bucket: node histogram ->
// exclusive scan -> rowlo/rowhi, then LDS-cursor scatter of 2B src ids.
__global__ __launch_bounds__(256) void k_nfill(
    const unsigned* __restrict__ pk, const int* __restrict__ bcur,
    int* __restrict__ rowlo, int* __restrict__ rowhi,
    unsigned short* __restrict__ csr, int nN) {
  __shared__ int hist[256];
  __shared__ int nbase[256];
  __shared__ int wsum[4];
  const int b = blockIdx.x;
  const int t = threadIdx.x;
  const int nb0 = b << 8;
  const int cnt = min(bcur[b], CAP);
  const unsigned gbase = (unsigned)b * CAP;
  hist[t] = 0;
  __syncthreads();
  for (int i = t; i < cnt; i += 256)
    atomicAdd(&hist[(pk[gbase + i] >> 16) & 255], 1);
  __syncthreads();
  const int lane = t & 63;
  const int wid = t >> 6;
  int v = hist[t];
  const int orig = v;
#pragma unroll
  for (int off = 1; off < 64; off <<= 1) {
    int u = __shfl_up(v, off);
    if (lane >= off) v += u;
  }
  if (lane == 63) wsum[wid] = v;
  __syncthreads();
  int add = 0;
  for (int w = 0; w < wid; ++w) add += wsum[w];
  const int excl = v - orig + add;
  nbase[t] = excl;
  if (nb0 + t < nN) {
    rowlo[nb0 + t] = (int)gbase + excl;
    rowhi[nb0 + t] = (int)gbase + excl + orig;
  }
  __syncthreads();
  hist[t] = 0;  // reuse as cursor
  __syncthreads();
  for (int i = t; i < cnt; i += 256) {
    unsigned p = pk[gbase + i];
    int dl = (p >> 16) & 255;
    int slot = nbase[dl] + atomicAdd(&hist[dl], 1);
    csr[gbase + slot] = (unsigned short)(p & 0xFFFFu);
  }
}

// K3: fused per-node online softmax (exp2 domain, 2-deep gather pipeline).
// One wave per node; 4 subgroups x 16 lanes; subgroup g walks edges
// lo+g, lo+g+4, ...; lane r owns channels 4r..4r+3.
__global__ __launch_bounds__(256) void k_node(
    const int* __restrict__ rowlo, const int* __restrict__ rowhi,
    const unsigned short* __restrict__ csr, const short* __restrict__ xlb,
    const float* __restrict__ xr, const float* __restrict__ att,
    const float* __restrict__ bias, float* __restrict__ out, int nN) {
  const int wid = (blockIdx.x * 256 + threadIdx.x) >> 6;  // node id
  if (wid >= nN) return;
  const int lane = threadIdx.x & 63;
  const int g = lane >> 4;
  const int r = lane & 15;
  const int d = wid;

  const float4 att4 = ((const float4*)att)[r];
  const float4 xr4 = *(const float4*)(xr + (size_t)d * 64 + r * 4);

  short4v sb = *(const short4v*)(xlb + (size_t)d * 64 + r * 4);
  float4 xls = make_float4(bf2f(sb[0]), bf2f(sb[1]), bf2f(sb[2]), bf2f(sb[3]));

  // self-loop logit (log2 domain)
  float hh, ps = 0.f;
  hh = xls.x + xr4.x; hh = fmaxf(hh, NEG_SLOPE * hh); ps = fmaf(hh, att4.x, ps);
  hh = xls.y + xr4.y; hh = fmaxf(hh, NEG_SLOPE * hh); ps = fmaf(hh, att4.y, ps);
  hh = xls.z + xr4.z; hh = fmaxf(hh, NEG_SLOPE * hh); ps = fmaf(hh, att4.z, ps);
  hh = xls.w + xr4.w; hh = fmaxf(hh, NEG_SLOPE * hh); ps = fmaf(hh, att4.w, ps);
  ps += __shfl_xor(ps, 1, 16);
  ps += __shfl_xor(ps, 2, 16);
  ps += __shfl_xor(ps, 4, 16);
  ps += __shfl_xor(ps, 8, 16);
  ps *= LOG2E;

  // m starts at the (finite) self logit for ALL subgroups -> inactive edges
  // get w = exp2(-3e38 - m) = 0 with no extra select hazard.
  const bool g0 = (g == 0);
  float m = ps;
  float ssum = g0 ? 1.f : 0.f;
  float4 acc = g0 ? xls : make_float4(0.f, 0.f, 0.f, 0.f);

  const int lo = rowlo[d], hi = rowhi[d];
  const int nst = (hi - lo + 3) >> 2;

#define PROC(VREG, SIDX)                                                      \
  {                                                                           \
    const bool act = ((SIDX) < hi);                                           \
    float4 xlv = make_float4(bf2f(VREG[0]), bf2f(VREG[1]), bf2f(VREG[2]),     \
                             bf2f(VREG[3]));                                  \
    float p = 0.f;                                                            \
    hh = xlv.x + xr4.x; hh = fmaxf(hh, NEG_SLOPE * hh);                       \
    p = fmaf(hh, att4.x, p);                                                  \
    hh = xlv.y + xr4.y; hh = fmaxf(hh, NEG_SLOPE * hh);                       \
    p = fmaf(hh, att4.y, p);                                                  \
    hh = xlv.z + xr4.z; hh = fmaxf(hh, NEG_SLOPE * hh);                       \
    p = fmaf(hh, att4.z, p);                                                  \
    hh = xlv.w + xr4.w; hh = fmaxf(hh, NEG_SLOPE * hh);                       \
    p = fmaf(hh, att4.w, p);                                                  \
    p += __shfl_xor(p, 1, 16);                                                \
    p += __shfl_xor(p, 2, 16);                                                \
    p += __shfl_xor(p, 4, 16);                                                \
    p += __shfl_xor(p, 8, 16);                                                \
    const float pm = act ? p * LOG2E : -3.0e38f;                              \
    const float nm = fmaxf(m, pm);                                            \
    const float sc = exp2f(m - nm);                                           \
    const float w = exp2f(pm - nm);                                           \
    ssum = fmaf(ssum, sc, w);                                                 \
    acc.x = fmaf(acc.x, sc, w * xlv.x);                                       \
    acc.y = fmaf(acc.y, sc, w * xlv.y);                                       \
    acc.z = fmaf(acc.z, sc, w * xlv.z);                                       \
    acc.w = fmaf(acc.w, sc, w * xlv.w);                                       \
    m = nm;                                                                   \
  }

  int sA = lo + g;
  int sB = sA + 4;
  int srcA = (sA < hi) ? (int)csr[sA] : d;
  short4v vA = *(const short4v*)(xlb + (size_t)srcA * 64 + r * 4);
  int srcB = (sB < hi) ? (int)csr[sB] : d;
  short4v vB = *(const short4v*)(xlb + (size_t)srcB * 64 + r * 4);

  int tt = 0;
  for (; tt + 1 < nst; tt += 2) {
    PROC(vA, sA);
    if (tt + 2 < nst) {
      int sN = sA + 8;
      int srcN = (sN < hi) ? (int)csr[sN] : d;
      vA = *(const short4v*)(xlb + (size_t)srcN * 64 + r * 4);
    }
    PROC(vB, sB);
    if (tt + 3 < nst) {
      int sN = sB + 8;
      int srcN = (sN < hi) ? (int)csr[sN] : d;
      vB = *(const short4v*)(xlb + (size_t)srcN * 64 + r * 4);
    }
    sA += 8;
    sB += 8;
  }
  if (tt < nst) PROC(vA, sA);
#undef PROC

  // merge 4 subgroup partials (butterfly over lane bits 4,5)
#pragma unroll
  for (int off = 16; off <= 32; off <<= 1) {
    float mo = __shfl_xor(m, off);
    float so = __shfl_xor(ssum, off);
    float ax = __shfl_xor(acc.x, off);
    float ay = __shfl_xor(acc.y, off);
    float az = __shfl_xor(acc.z, off);
    float aw = __shfl_xor(acc.w, off);
    float nm = fmaxf(m, mo);
    float sa = exp2f(m - nm);
    float sb2 = exp2f(mo - nm);
    ssum = ssum * sa + so * sb2;
    acc.x = acc.x * sa + ax * sb2;
    acc.y = acc.y * sa + ay * sb2;
    acc.z = acc.z * sa + az * sb2;
    acc.w = acc.w * sa + aw * sb2;
    m = nm;
  }

  if (g == 0) {
    const float inv = 1.0f / ssum;
    const float4 b4 = ((const float4*)bias)[r];
    float4 o;
    o.x = fmaxf(fmaf(acc.x, inv, b4.x), 0.f);
    o.y = fmaxf(fmaf(acc.y, inv, b4.y), 0.f);
    o.z = fmaxf(fmaf(acc.z, inv, b4.z), 0.f);
    o.w = fmaxf(fmaf(acc.w, inv, b4.w), 0.f);
    *(float4*)(out + (size_t)d * 64 + r * 4) = o;
  }
}

extern "C" void kernel_launch(void* const* d_in, const int* in_sizes, int n_in,
                              void* d_out, int out_size, void* d_ws,
                              size_t ws_size, hipStream_t stream) {
  const float* x    = (const float*)d_in[0];
  const float* Wl   = (const float*)d_in[1];
  const float* bl   = (const float*)d_in[2];
  const float* Wr   = (const float*)d_in[3];
  const float* br   = (const float*)d_in[4];
  const float* att  = (const float*)d_in[5];
  const float* bias = (const float*)d_in[6];
  const int* eidx   = (const int*)d_in[7];
  float* out = (float*)d_out;

  const int N = in_sizes[0] / 128;   // 50000 (< 65536 required for packing)
  const int E = in_sizes[7] / 2;     // 800000
  const int NB = (N + 255) >> 8;     // 196 node buckets
  const int nbf = (E + CHUNK - 1) / CHUNK;          // 196 bfill blocks
  const int ntr = (((N + 15) / 16) * 8 + 3) / 4;    // 6250 transform blocks

  // ---- workspace layout ----
  short* xlb   = (short*)d_ws;                        // N*64 bf16
  float* xr    = (float*)(xlb + (size_t)N * 64);      // N*64 f32
  unsigned* pk = (unsigned*)(xr + (size_t)N * 64);    // NB*CAP u32
  unsigned short* csr = (unsigned short*)(pk + (size_t)NB * CAP);  // NB*CAP u16
  int* bcur    = (int*)(csr + (size_t)NB * CAP);      // NB
  int* rowlo   = bcur + NB;                           // N
  int* rowhi   = rowlo + N;                           // N

  k_zero<<<1, 256, 0, stream>>>(bcur, NB);
  k_tb<<<nbf + ntr, 256, 0, stream>>>(x, Wl, Wr, bl, br, eidx, bcur, pk, xlb,
                                      xr, N, E, nbf);
  k_nfill<<<NB, 256, 0, stream>>>(pk, bcur, rowlo, rowhi, csr, N);
  k_node<<<(N + 3) / 4, 256, 0, stream>>>(rowlo, rowhi, csr, xlb, xr, att,
                                          bias, out, N);
}

// Round 9
// 83.906 us; speedup vs baseline: 1.3224x; 1.3224x over previous
//
#include <hip/hip_runtime.h>
#include <hip/hip_bf16.h>

#define NEG_SLOPE 0.2f
#define CAP 5120          // per-bucket capacity (avg 4096, ~16-sigma margin)
#define CHUNK 4096        // edges per workgroup in k_bfill
#define LOG2E 1.4426950408889634f

typedef __attribute__((ext_vector_type(8))) short short8v;
typedef __attribute__((ext_vector_type(4))) short short4v;
typedef __attribute__((ext_vector_type(4))) float f32x4;

__device__ __forceinline__ short f2bf(float f) {
  __hip_bfloat16 b = __float2bfloat16(f);  // RNE
  return *reinterpret_cast<short*>(&b);
}
__device__ __forceinline__ float bf2f(short s) {
  return __uint_as_float(((unsigned)(unsigned short)s) << 16);
}

// K0: Wl||Wr -> W2[128ch][128k] bf16 (B-fragment layout), biasc, zero bcur.
__global__ __launch_bounds__(256) void k_prep(
    const float* __restrict__ Wl, const float* __restrict__ Wr,
    const float* __restrict__ bl, const float* __restrict__ br,
    short* __restrict__ W2, float* __restrict__ biasc,
    int* __restrict__ bcur, int nbk) {
  int idx = blockIdx.x * 256 + threadIdx.x;
  if (idx < 128 * 128) {
    int j = idx >> 7, k = idx & 127;
    float v = (j < 64) ? Wl[j * 128 + k] : Wr[(j - 64) * 128 + k];
    W2[idx] = f2bf(v);
  } else {
    int z = idx - 128 * 128;
    if (z < nbk) bcur[z] = 0;
  }
  if (idx < 128) biasc[idx] = (idx < 64) ? bl[idx] : br[idx - 64];
}

// K1: LDS-staged MFMA transform. 64 nodes x 128 ch per block (4 waves).
// x-tile staged coalesced f32->bf16 into xs[64][136] (row pad +8 shorts ->
// 272B stride: ds_read_b128 A-frags hit the 8-dword/bank structural minimum).
// Wave w computes ch-tiles {2w, 2w+1} x 4 node-tiles; B-frags from L1-hot W2.
__global__ __launch_bounds__(256) void k_transform(
    const float* __restrict__ x, const short* __restrict__ W2,
    const float* __restrict__ biasc, short* __restrict__ xlb,
    float* __restrict__ xr, int nN) {
  __shared__ short xs[64 * 136];
  const int t = threadIdx.x;
  const int n0 = blockIdx.x * 64;
#pragma unroll
  for (int i = 0; i < 8; ++i) {
    int f = (i * 256 + t) * 4;        // flat f32 index into 64x128 tile
    int node = f >> 7, k = f & 127;
    int gn = min(n0 + node, nN - 1);
    float4 v = *(const float4*)(x + (size_t)gn * 128 + k);
    short4v s4;
    s4[0] = f2bf(v.x); s4[1] = f2bf(v.y); s4[2] = f2bf(v.z); s4[3] = f2bf(v.w);
    *(short4v*)(xs + node * 136 + k) = s4;
  }
  __syncthreads();

  const int w = t >> 6;
  const int lane = t & 63;
  const int r = lane & 15;
  const int kb = lane >> 4;

  short8v bfr[2][4];
#pragma unroll
  for (int c = 0; c < 2; ++c) {
    const short* bp = W2 + (size_t)((w * 2 + c) * 16 + r) * 128 + kb * 8;
#pragma unroll
    for (int kk = 0; kk < 4; ++kk) bfr[c][kk] = *(const short8v*)(bp + kk * 32);
  }

  f32x4 acc[4][2];
#pragma unroll
  for (int nt = 0; nt < 4; ++nt)
#pragma unroll
    for (int c = 0; c < 2; ++c) acc[nt][c] = (f32x4){0.f, 0.f, 0.f, 0.f};

#pragma unroll
  for (int nt = 0; nt < 4; ++nt) {
    short8v afr[4];
#pragma unroll
    for (int kk = 0; kk < 4; ++kk)
      afr[kk] =
          *(const short8v*)(xs + (nt * 16 + r) * 136 + kb * 8 + kk * 32);
#pragma unroll
    for (int kk = 0; kk < 4; ++kk) {
      acc[nt][0] =
          __builtin_amdgcn_mfma_f32_16x16x32_bf16(afr[kk], bfr[0][kk],
                                                  acc[nt][0], 0, 0, 0);
      acc[nt][1] =
          __builtin_amdgcn_mfma_f32_16x16x32_bf16(afr[kk], bfr[1][kk],
                                                  acc[nt][1], 0, 0, 0);
    }
  }

#pragma unroll
  for (int c = 0; c < 2; ++c) {
    const int ch = (w * 2 + c) * 16 + r;
    const float bv = biasc[ch];
#pragma unroll
    for (int nt = 0; nt < 4; ++nt) {
#pragma unroll
      for (int i = 0; i < 4; ++i) {
        int node = n0 + nt * 16 + kb * 4 + i;
        if (node < nN) {
          float v = acc[nt][c][i] + bv;
          if (ch < 64) xlb[(size_t)node * 64 + ch] = f2bf(v);
          else         xr[(size_t)node * 64 + (ch - 64)] = v;
        }
      }
    }
  }
}

// K2: bucketed edge fill (bucket = dst>>8). LDS histogram+rank -> one global
// atomicAdd per (WG,bucket) -> contiguous packed writes. pack=(dst<<16)|src.
__global__ __launch_bounds__(256) void k_bfill(
    const int* __restrict__ eidx, int* __restrict__ bcur,
    unsigned* __restrict__ pk, int E_) {
  __shared__ int hist[256];
  __shared__ int base[256];
  const int t = threadIdx.x;
  hist[t] = 0;
  __syncthreads();
  const int e0 = blockIdx.x * CHUNK + t * 16;
  unsigned mypk[16];
  int myrank[16];
  const bool valid = (e0 < E_);  // E_ % 16 == 0 -> all-or-nothing per thread
  if (valid) {
    const int4* ps = (const int4*)(eidx + e0);
    const int4* pd = (const int4*)(eidx + E_ + e0);
#pragma unroll
    for (int j = 0; j < 4; ++j) {
      int4 sv = ps[j];
      int4 dv = pd[j];
      int ss[4] = {sv.x, sv.y, sv.z, sv.w};
      int dd[4] = {dv.x, dv.y, dv.z, dv.w};
#pragma unroll
      for (int q = 0; q < 4; ++q) {
        unsigned p = ((unsigned)dd[q] << 16) | (unsigned)ss[q];
        mypk[j * 4 + q] = p;
        myrank[j * 4 + q] = atomicAdd(&hist[dd[q] >> 8], 1);
      }
    }
  }
  __syncthreads();
  base[t] = hist[t] ? atomicAdd(&bcur[t], hist[t]) : 0;
  __syncthreads();
  if (valid) {
#pragma unroll
    for (int j = 0; j < 16; ++j) {
      int b = mypk[j] >> 24;
      unsigned idx = (unsigned)(base[b] + myrank[j]);
      if (idx < CAP) pk[(unsigned)b * CAP + idx] = mypk[j];
    }
  }
}

// K3: per-bucket finalize: node histogram -> scan -> rowlo/rowhi -> 2B csr.
__global__ __launch_bounds__(256) void k_nfill(
    const unsigned* __restrict__ pk, const int* __restrict__ bcur,
    int* __restrict__ rowlo, int* __restrict__ rowhi,
    unsigned short* __restrict__ csr, int nN) {
  __shared__ int hist[256];
  __shared__ int nbase[256];
  __shared__ int wsum[4];
  const int b = blockIdx.x;
  const int t = threadIdx.x;
  const int nb0 = b << 8;
  const int cnt = min(bcur[b], CAP);
  const unsigned gbase = (unsigned)b * CAP;
  hist[t] = 0;
  __syncthreads();
  for (int i = t; i < cnt; i += 256)
    atomicAdd(&hist[(pk[gbase + i] >> 16) & 255], 1);
  __syncthreads();
  const int lane = t & 63;
  const int wid = t >> 6;
  int v = hist[t];
  const int orig = v;
#pragma unroll
  for (int off = 1; off < 64; off <<= 1) {
    int u = __shfl_up(v, off);
    if (lane >= off) v += u;
  }
  if (lane == 63) wsum[wid] = v;
  __syncthreads();
  int add = 0;
  for (int ww = 0; ww < wid; ++ww) add += wsum[ww];
  const int excl = v - orig + add;
  nbase[t] = excl;
  if (nb0 + t < nN) {
    rowlo[nb0 + t] = (int)gbase + excl;
    rowhi[nb0 + t] = (int)gbase + excl + orig;
  }
  __syncthreads();
  hist[t] = 0;  // reuse as cursor
  __syncthreads();
  for (int i = t; i < cnt; i += 256) {
    unsigned p = pk[gbase + i];
    int dl = (p >> 16) & 255;
    int slot = nbase[dl] + atomicAdd(&hist[dl], 1);
    csr[gbase + slot] = (unsigned short)(p & 0xFFFFu);
  }
}

// K4: fused per-node online softmax (exp2 domain, 2-deep gather pipeline).
__global__ __launch_bounds__(256) void k_node(
    const int* __restrict__ rowlo, const int* __restrict__ rowhi,
    const unsigned short* __restrict__ csr, const short* __restrict__ xlb,
    const float* __restrict__ xr, const float* __restrict__ att,
    const float* __restrict__ bias, float* __restrict__ out, int nN) {
  const int wid = (blockIdx.x * 256 + threadIdx.x) >> 6;  // node id
  if (wid >= nN) return;
  const int lane = threadIdx.x & 63;
  const int g = lane >> 4;
  const int r = lane & 15;
  const int d = wid;

  const float4 att4 = ((const float4*)att)[r];
  const float4 xr4 = *(const float4*)(xr + (size_t)d * 64 + r * 4);

  short4v sb = *(const short4v*)(xlb + (size_t)d * 64 + r * 4);
  float4 xls = make_float4(bf2f(sb[0]), bf2f(sb[1]), bf2f(sb[2]), bf2f(sb[3]));

  float hh, ps = 0.f;
  hh = xls.x + xr4.x; hh = fmaxf(hh, NEG_SLOPE * hh); ps = fmaf(hh, att4.x, ps);
  hh = xls.y + xr4.y; hh = fmaxf(hh, NEG_SLOPE * hh); ps = fmaf(hh, att4.y, ps);
  hh = xls.z + xr4.z; hh = fmaxf(hh, NEG_SLOPE * hh); ps = fmaf(hh, att4.z, ps);
  hh = xls.w + xr4.w; hh = fmaxf(hh, NEG_SLOPE * hh); ps = fmaf(hh, att4.w, ps);
  ps += __shfl_xor(ps, 1, 16);
  ps += __shfl_xor(ps, 2, 16);
  ps += __shfl_xor(ps, 4, 16);
  ps += __shfl_xor(ps, 8, 16);
  ps *= LOG2E;

  const bool g0 = (g == 0);
  float m = ps;
  float ssum = g0 ? 1.f : 0.f;
  float4 acc = g0 ? xls : make_float4(0.f, 0.f, 0.f, 0.f);

  const int lo = rowlo[d], hi = rowhi[d];
  const int nst = (hi - lo + 3) >> 2;

#define PROC(VREG, SIDX)                                                      \
  {                                                                           \
    const bool act = ((SIDX) < hi);                                           \
    float4 xlv = make_float4(bf2f(VREG[0]), bf2f(VREG[1]), bf2f(VREG[2]),     \
                             bf2f(VREG[3]));                                  \
    float p = 0.f;                                                            \
    hh = xlv.x + xr4.x; hh = fmaxf(hh, NEG_SLOPE * hh);                       \
    p = fmaf(hh, att4.x, p);                                                  \
    hh = xlv.y + xr4.y; hh = fmaxf(hh, NEG_SLOPE * hh);                       \
    p = fmaf(hh, att4.y, p);                                                  \
    hh = xlv.z + xr4.z; hh = fmaxf(hh, NEG_SLOPE * hh);                       \
    p = fmaf(hh, att4.z, p);                                                  \
    hh = xlv.w + xr4.w; hh = fmaxf(hh, NEG_SLOPE * hh);                       \
    p = fmaf(hh, att4.w, p);                                                  \
    p += __shfl_xor(p, 1, 16);                                                \
    p += __shfl_xor(p, 2, 16);                                                \
    p += __shfl_xor(p, 4, 16);                                                \
    p += __shfl_xor(p, 8, 16);                                                \
    const float pm = act ? p * LOG2E : -3.0e38f;                              \
    const float nm = fmaxf(m, pm);                                            \
    const float sc = exp2f(m - nm);                                           \
    const float w = exp2f(pm - nm);                                           \
    ssum = fmaf(ssum, sc, w);                                                 \
    acc.x = fmaf(acc.x, sc, w * xlv.x);                                       \
    acc.y = fmaf(acc.y, sc, w * xlv.y);                                       \
    acc.z = fmaf(acc.z, sc, w * xlv.z);                                       \
    acc.w = fmaf(acc.w, sc, w * xlv.w);                                       \
    m = nm;                                                                   \
  }

  int sA = lo + g;
  int sB = sA + 4;
  int srcA = (sA < hi) ? (int)csr[sA] : d;
  short4v vA = *(const short4v*)(xlb + (size_t)srcA * 64 + r * 4);
  int srcB = (sB < hi) ? (int)csr[sB] : d;
  short4v vB = *(const short4v*)(xlb + (size_t)srcB * 64 + r * 4);

  int tt = 0;
  for (; tt + 1 < nst; tt += 2) {
    PROC(vA, sA);
    if (tt + 2 < nst) {
      int sN = sA + 8;
      int srcN = (sN < hi) ? (int)csr[sN] : d;
      vA = *(const short4v*)(xlb + (size_t)srcN * 64 + r * 4);
    }
    PROC(vB, sB);
    if (tt + 3 < nst) {
      int sN = sB + 8;
      int srcN = (sN < hi) ? (int)csr[sN] : d;
      vB = *(const short4v*)(xlb + (size_t)srcN * 64 + r * 4);
    }
    sA += 8;
    sB += 8;
  }
  if (tt < nst) PROC(vA, sA);
#undef PROC

#pragma unroll
  for (int off = 16; off <= 32; off <<= 1) {
    float mo = __shfl_xor(m, off);
    float so = __shfl_xor(ssum, off);
    float ax = __shfl_xor(acc.x, off);
    float ay = __shfl_xor(acc.y, off);
    float az = __shfl_xor(acc.z, off);
    float aw = __shfl_xor(acc.w, off);
    float nm = fmaxf(m, mo);
    float sa = exp2f(m - nm);
    float sb2 = exp2f(mo - nm);
    ssum = ssum * sa + so * sb2;
    acc.x = acc.x * sa + ax * sb2;
    acc.y = acc.y * sa + ay * sb2;
    acc.z = acc.z * sa + az * sb2;
    acc.w = acc.w * sa + aw * sb2;
    m = nm;
  }

  if (g == 0) {
    const float inv = 1.0f / ssum;
    const float4 b4 = ((const float4*)bias)[r];
    float4 o;
    o.x = fmaxf(fmaf(acc.x, inv, b4.x), 0.f);
    o.y = fmaxf(fmaf(acc.y, inv, b4.y), 0.f);
    o.z = fmaxf(fmaf(acc.z, inv, b4.z), 0.f);
    o.w = fmaxf(fmaf(acc.w, inv, b4.w), 0.f);
    *(float4*)(out + (size_t)d * 64 + r * 4) = o;
  }
}

extern "C" void kernel_launch(void* const* d_in, const int* in_sizes, int n_in,
                              void* d_out, int out_size, void* d_ws,
                              size_t ws_size, hipStream_t stream) {
  const float* x    = (const float*)d_in[0];
  const float* Wl   = (const float*)d_in[1];
  const float* bl   = (const float*)d_in[2];
  const float* Wr   = (const float*)d_in[3];
  const float* br   = (const float*)d_in[4];
  const float* att  = (const float*)d_in[5];
  const float* bias = (const float*)d_in[6];
  const int* eidx   = (const int*)d_in[7];
  float* out = (float*)d_out;

  const int N = in_sizes[0] / 128;   // 50000 (< 65536 required for packing)
  const int E = in_sizes[7] / 2;     // 800000
  const int NB = (N + 255) >> 8;     // 196 node buckets

  // ---- workspace layout ----
  short* xlb   = (short*)d_ws;                        // N*64 bf16
  float* xr    = (float*)(xlb + (size_t)N * 64);      // N*64 f32
  unsigned* pk = (unsigned*)(xr + (size_t)N * 64);    // NB*CAP u32
  unsigned short* csr = (unsigned short*)(pk + (size_t)NB * CAP);  // NB*CAP u16
  short* W2    = (short*)(csr + (size_t)NB * CAP);    // 128*128 bf16
  float* biasc = (float*)(W2 + 128 * 128);            // 128 f32
  int* bcur    = (int*)(biasc + 128);                 // NB
  int* rowlo   = bcur + NB;                           // N
  int* rowhi   = rowlo + N;                           // N

  k_prep<<<(128 * 128 + NB + 255) / 256, 256, 0, stream>>>(
      Wl, Wr, bl, br, W2, biasc, bcur, NB);
  k_transform<<<(N + 63) / 64, 256, 0, stream>>>(x, W2, biasc, xlb, xr, N);
  k_bfill<<<(E + CHUNK - 1) / CHUNK, 256, 0, stream>>>(eidx, bcur, pk, E);
  k_nfill<<<NB, 256, 0, stream>>>(pk, bcur, rowlo, rowhi, csr, N);
  k_node<<<(N + 3) / 4, 256, 0, stream>>>(rowlo, rowhi, csr, xlb, xr, att,
                                          bias, out, N);
}

// Round 10
// 82.060 us; speedup vs baseline: 1.3521x; 1.0225x over previous
//
#include <hip/hip_runtime.h>
#include <hip/hip_bf16.h>

#define NEG_SLOPE 0.2f
#define CAP 5120          // per-bucket capacity (avg 4096, ~16-sigma margin)
#define CHUNK 4096        // edges per workgroup in bfill path
#define LOG2E 1.4426950408889634f

typedef __attribute__((ext_vector_type(8))) short short8v;
typedef __attribute__((ext_vector_type(4))) short short4v;
typedef __attribute__((ext_vector_type(4))) float f32x4;

__device__ __forceinline__ short f2bf(float f) {
  __hip_bfloat16 b = __float2bfloat16(f);  // RNE
  return *reinterpret_cast<short*>(&b);
}
__device__ __forceinline__ float bf2f(short s) {
  return __uint_as_float(((unsigned)(unsigned short)s) << 16);
}

// 16-lane sum reduction entirely in the VALU pipe via DPP (no ds_swizzle):
// quad_perm xor1, xor2 give quad sums; row_ror:4 + row_ror:8 accumulate the
// four quad sums into every lane of the 16-lane row.
__device__ __forceinline__ float row_reduce16(float p) {
  p += __int_as_float(__builtin_amdgcn_update_dpp(
      0, __float_as_int(p), 0xB1, 0xF, 0xF, true));   // quad_perm [1,0,3,2]
  p += __int_as_float(__builtin_amdgcn_update_dpp(
      0, __float_as_int(p), 0x4E, 0xF, 0xF, true));   // quad_perm [2,3,0,1]
  p += __int_as_float(__builtin_amdgcn_update_dpp(
      0, __float_as_int(p), 0x124, 0xF, 0xF, true));  // row_ror:4
  p += __int_as_float(__builtin_amdgcn_update_dpp(
      0, __float_as_int(p), 0x128, 0xF, 0xF, true));  // row_ror:8
  return p;
}

// K0: Wl||Wr -> W2[128ch][128k] bf16 (B-fragment layout), biasc, zero bcur.
__global__ __launch_bounds__(256) void k_prep(
    const float* __restrict__ Wl, const float* __restrict__ Wr,
    const float* __restrict__ bl, const float* __restrict__ br,
    short* __restrict__ W2, float* __restrict__ biasc,
    int* __restrict__ bcur, int nbk) {
  int idx = blockIdx.x * 256 + threadIdx.x;
  if (idx < 128 * 128) {
    int j = idx >> 7, k = idx & 127;
    float v = (j < 64) ? Wl[j * 128 + k] : Wr[(j - 64) * 128 + k];
    W2[idx] = f2bf(v);
  } else {
    int z = idx - 128 * 128;
    if (z < nbk) bcur[z] = 0;
  }
  if (idx < 128) biasc[idx] = (idx < 64) ? bl[idx] : br[idx - 64];
}

// K1 fused: blocks [0,nbf) = bucketed edge fill; blocks [nbf,..) = LDS-staged
// MFMA transform. Independent work co-scheduled; LDS unioned.
__global__ __launch_bounds__(256) void k_tbf(
    const float* __restrict__ x, const short* __restrict__ W2,
    const float* __restrict__ biasc, const int* __restrict__ eidx,
    int* __restrict__ bcur, unsigned* __restrict__ pk,
    short* __restrict__ xlb, float* __restrict__ xr, int nN, int E_,
    int nbf) {
  __shared__ union {
    struct { int hist[256]; int base[256]; } bf;
    short xs[64 * 136];
  } u;
  const int t = threadIdx.x;

  if (blockIdx.x < nbf) {
    // ---------------- bfill path ----------------
    u.bf.hist[t] = 0;
    __syncthreads();
    const int e0 = blockIdx.x * CHUNK + t * 16;
    unsigned mypk[16];
    int myrank[16];
    const bool valid = (e0 < E_);  // E_ % 16 == 0 -> all-or-nothing per thread
    if (valid) {
      const int4* ps = (const int4*)(eidx + e0);
      const int4* pd = (const int4*)(eidx + E_ + e0);
#pragma unroll
      for (int j = 0; j < 4; ++j) {
        int4 sv = ps[j];
        int4 dv = pd[j];
        int ss[4] = {sv.x, sv.y, sv.z, sv.w};
        int dd[4] = {dv.x, dv.y, dv.z, dv.w};
#pragma unroll
        for (int q = 0; q < 4; ++q) {
          unsigned p = ((unsigned)dd[q] << 16) | (unsigned)ss[q];
          mypk[j * 4 + q] = p;
          myrank[j * 4 + q] = atomicAdd(&u.bf.hist[dd[q] >> 8], 1);
        }
      }
    }
    __syncthreads();
    u.bf.base[t] = u.bf.hist[t] ? atomicAdd(&bcur[t], u.bf.hist[t]) : 0;
    __syncthreads();
    if (valid) {
#pragma unroll
      for (int j = 0; j < 16; ++j) {
        int b = mypk[j] >> 24;
        unsigned idx = (unsigned)(u.bf.base[b] + myrank[j]);
        if (idx < CAP) pk[(unsigned)b * CAP + idx] = mypk[j];
      }
    }
    return;
  }

  // ---------------- transform path ----------------
  const int n0 = (blockIdx.x - nbf) * 64;
#pragma unroll
  for (int i = 0; i < 8; ++i) {
    int f = (i * 256 + t) * 4;        // flat f32 index into 64x128 tile
    int node = f >> 7, k = f & 127;
    int gn = min(n0 + node, nN - 1);
    float4 v = *(const float4*)(x + (size_t)gn * 128 + k);
    short4v s4;
    s4[0] = f2bf(v.x); s4[1] = f2bf(v.y); s4[2] = f2bf(v.z); s4[3] = f2bf(v.w);
    *(short4v*)(u.xs + node * 136 + k) = s4;
  }
  __syncthreads();

  const int w = t >> 6;
  const int lane = t & 63;
  const int r = lane & 15;
  const int kb = lane >> 4;

  short8v bfr[2][4];
#pragma unroll
  for (int c = 0; c < 2; ++c) {
    const short* bp = W2 + (size_t)((w * 2 + c) * 16 + r) * 128 + kb * 8;
#pragma unroll
    for (int kk = 0; kk < 4; ++kk) bfr[c][kk] = *(const short8v*)(bp + kk * 32);
  }

  f32x4 acc[4][2];
#pragma unroll
  for (int nt = 0; nt < 4; ++nt)
#pragma unroll
    for (int c = 0; c < 2; ++c) acc[nt][c] = (f32x4){0.f, 0.f, 0.f, 0.f};

#pragma unroll
  for (int nt = 0; nt < 4; ++nt) {
    short8v afr[4];
#pragma unroll
    for (int kk = 0; kk < 4; ++kk)
      afr[kk] =
          *(const short8v*)(u.xs + (nt * 16 + r) * 136 + kb * 8 + kk * 32);
#pragma unroll
    for (int kk = 0; kk < 4; ++kk) {
      acc[nt][0] =
          __builtin_amdgcn_mfma_f32_16x16x32_bf16(afr[kk], bfr[0][kk],
                                                  acc[nt][0], 0, 0, 0);
      acc[nt][1] =
          __builtin_amdgcn_mfma_f32_16x16x32_bf16(afr[kk], bfr[1][kk],
                                                  acc[nt][1], 0, 0, 0);
    }
  }

#pragma unroll
  for (int c = 0; c < 2; ++c) {
    const int ch = (w * 2 + c) * 16 + r;
    const float bv = biasc[ch];
#pragma unroll
    for (int nt = 0; nt < 4; ++nt) {
#pragma unroll
      for (int i = 0; i < 4; ++i) {
        int node = n0 + nt * 16 + kb * 4 + i;
        if (node < nN) {
          float v = acc[nt][c][i] + bv;
          if (ch < 64) xlb[(size_t)node * 64 + ch] = f2bf(v);
          else         xr[(size_t)node * 64 + (ch - 64)] = v;
        }
      }
    }
  }
}

// K2: per-bucket finalize: node histogram -> scan -> rowlo/rowhi -> 2B csr.
__global__ __launch_bounds__(256) void k_nfill(
    const unsigned* __restrict__ pk, const int* __restrict__ bcur,
    int* __restrict__ rowlo, int* __restrict__ rowhi,
    unsigned short* __restrict__ csr, int nN) {
  __shared__ int hist[256];
  __shared__ int nbase[256];
  __shared__ int wsum[4];
  const int b = blockIdx.x;
  const int t = threadIdx.x;
  const int nb0 = b << 8;
  const int cnt = min(bcur[b], CAP);
  const unsigned gbase = (unsigned)b * CAP;
  hist[t] = 0;
  __syncthreads();
  for (int i = t; i < cnt; i += 256)
    atomicAdd(&hist[(pk[gbase + i] >> 16) & 255], 1);
  __syncthreads();
  const int lane = t & 63;
  const int wid = t >> 6;
  int v = hist[t];
  const int orig = v;
#pragma unroll
  for (int off = 1; off < 64; off <<= 1) {
    int uu = __shfl_up(v, off);
    if (lane >= off) v += uu;
  }
  if (lane == 63) wsum[wid] = v;
  __syncthreads();
  int add = 0;
  for (int ww = 0; ww < wid; ++ww) add += wsum[ww];
  const int excl = v - orig + add;
  nbase[t] = excl;
  if (nb0 + t < nN) {
    rowlo[nb0 + t] = (int)gbase + excl;
    rowhi[nb0 + t] = (int)gbase + excl + orig;
  }
  __syncthreads();
  hist[t] = 0;  // reuse as cursor
  __syncthreads();
  for (int i = t; i < cnt; i += 256) {
    unsigned p = pk[gbase + i];
    int dl = (p >> 16) & 255;
    int slot = nbase[dl] + atomicAdd(&hist[dl], 1);
    csr[gbase + slot] = (unsigned short)(p & 0xFFFFu);
  }
}

// K3: fused per-node online softmax (exp2 domain, DPP row-reduce, 4-deep
// gather pipeline). One wave per node; 4 subgroups x 16 lanes; subgroup g
// walks edges lo+g, lo+g+4, ...; lane r owns channels 4r..4r+3.
__global__ __launch_bounds__(256) void k_node(
    const int* __restrict__ rowlo, const int* __restrict__ rowhi,
    const unsigned short* __restrict__ csr, const short* __restrict__ xlb,
    const float* __restrict__ xr, const float* __restrict__ att,
    const float* __restrict__ bias, float* __restrict__ out, int nN) {
  const int wid = (blockIdx.x * 256 + threadIdx.x) >> 6;  // node id
  if (wid >= nN) return;
  const int lane = threadIdx.x & 63;
  const int g = lane >> 4;
  const int r = lane & 15;
  const int d = wid;

  const float4 att4 = ((const float4*)att)[r];
  const float4 xr4 = *(const float4*)(xr + (size_t)d * 64 + r * 4);

  short4v sb = *(const short4v*)(xlb + (size_t)d * 64 + r * 4);
  float4 xls = make_float4(bf2f(sb[0]), bf2f(sb[1]), bf2f(sb[2]), bf2f(sb[3]));

  float hh, ps = 0.f;
  hh = xls.x + xr4.x; hh = fmaxf(hh, NEG_SLOPE * hh); ps = fmaf(hh, att4.x, ps);
  hh = xls.y + xr4.y; hh = fmaxf(hh, NEG_SLOPE * hh); ps = fmaf(hh, att4.y, ps);
  hh = xls.z + xr4.z; hh = fmaxf(hh, NEG_SLOPE * hh); ps = fmaf(hh, att4.z, ps);
  hh = xls.w + xr4.w; hh = fmaxf(hh, NEG_SLOPE * hh); ps = fmaf(hh, att4.w, ps);
  ps = row_reduce16(ps) * LOG2E;

  const bool g0 = (g == 0);
  float m = ps;
  float ssum = g0 ? 1.f : 0.f;
  float4 acc = g0 ? xls : make_float4(0.f, 0.f, 0.f, 0.f);

  const int lo = rowlo[d], hi = rowhi[d];
  const int nst = (hi - lo + 3) >> 2;

#define PROC(VREG, SIDX)                                                      \
  {                                                                           \
    const bool act = ((SIDX) < hi);                                           \
    float4 xlv = make_float4(bf2f(VREG[0]), bf2f(VREG[1]), bf2f(VREG[2]),     \
                             bf2f(VREG[3]));                                  \
    float p = 0.f;                                                            \
    hh = xlv.x + xr4.x; hh = fmaxf(hh, NEG_SLOPE * hh);                       \
    p = fmaf(hh, att4.x, p);                                                  \
    hh = xlv.y + xr4.y; hh = fmaxf(hh, NEG_SLOPE * hh);                       \
    p = fmaf(hh, att4.y, p);                                                  \
    hh = xlv.z + xr4.z; hh = fmaxf(hh, NEG_SLOPE * hh);                       \
    p = fmaf(hh, att4.z, p);                                                  \
    hh = xlv.w + xr4.w; hh = fmaxf(hh, NEG_SLOPE * hh);                       \
    p = fmaf(hh, att4.w, p);                                                  \
    p = row_reduce16(p);                                                      \
    const float pm = act ? p * LOG2E : -3.0e38f;                              \
    const float nm = fmaxf(m, pm);                                            \
    const float sc = exp2f(m - nm);                                           \
    const float w = exp2f(pm - nm);                                           \
    ssum = fmaf(ssum, sc, w);                                                 \
    acc.x = fmaf(acc.x, sc, w * xlv.x);                                       \
    acc.y = fmaf(acc.y, sc, w * xlv.y);                                       \
    acc.z = fmaf(acc.z, sc, w * xlv.z);                                       \
    acc.w = fmaf(acc.w, sc, w * xlv.w);                                       \
    m = nm;                                                                   \
  }

  int sA = lo + g, sB = sA + 4, sC = sA + 8, sD = sA + 12;
  short4v vA, vB, vC, vD;
  {
    int srcA = (sA < hi) ? (int)csr[sA] : d;
    vA = *(const short4v*)(xlb + (size_t)srcA * 64 + r * 4);
    int srcB = (sB < hi) ? (int)csr[sB] : d;
    vB = *(const short4v*)(xlb + (size_t)srcB * 64 + r * 4);
    int srcC = (sC < hi) ? (int)csr[sC] : d;
    vC = *(const short4v*)(xlb + (size_t)srcC * 64 + r * 4);
    int srcD = (sD < hi) ? (int)csr[sD] : d;
    vD = *(const short4v*)(xlb + (size_t)srcD * 64 + r * 4);
  }

  int tt = 0;
  for (; tt + 3 < nst; tt += 4) {
    PROC(vA, sA);
    if (tt + 4 < nst) {
      int sN = sA + 16;
      int srcN = (sN < hi) ? (int)csr[sN] : d;
      vA = *(const short4v*)(xlb + (size_t)srcN * 64 + r * 4);
    }
    PROC(vB, sB);
    if (tt + 5 < nst) {
      int sN = sB + 16;
      int srcN = (sN < hi) ? (int)csr[sN] : d;
      vB = *(const short4v*)(xlb + (size_t)srcN * 64 + r * 4);
    }
    PROC(vC, sC);
    if (tt + 6 < nst) {
      int sN = sC + 16;
      int srcN = (sN < hi) ? (int)csr[sN] : d;
      vC = *(const short4v*)(xlb + (size_t)srcN * 64 + r * 4);
    }
    PROC(vD, sD);
    if (tt + 7 < nst) {
      int sN = sD + 16;
      int srcN = (sN < hi) ? (int)csr[sN] : d;
      vD = *(const short4v*)(xlb + (size_t)srcN * 64 + r * 4);
    }
    sA += 16; sB += 16; sC += 16; sD += 16;
  }
  {
    const int rem = nst - tt;
    if (rem > 0) PROC(vA, sA);
    if (rem > 1) PROC(vB, sB);
    if (rem > 2) PROC(vC, sC);
  }
#undef PROC

  // merge 4 subgroup partials (crosses 16-lane rows -> shfl, once per wave)
#pragma unroll
  for (int off = 16; off <= 32; off <<= 1) {
    float mo = __shfl_xor(m, off);
    float so = __shfl_xor(ssum, off);
    float ax = __shfl_xor(acc.x, off);
    float ay = __shfl_xor(acc.y, off);
    float az = __shfl_xor(acc.z, off);
    float aw = __shfl_xor(acc.w, off);
    float nm = fmaxf(m, mo);
    float sa = exp2f(m - nm);
    float sb2 = exp2f(mo - nm);
    ssum = ssum * sa + so * sb2;
    acc.x = acc.x * sa + ax * sb2;
    acc.y = acc.y * sa + ay * sb2;
    acc.z = acc.z * sa + az * sb2;
    acc.w = acc.w * sa + aw * sb2;
    m = nm;
  }

  if (g == 0) {
    const float inv = 1.0f / ssum;
    const float4 b4 = ((const float4*)bias)[r];
    float4 o;
    o.x = fmaxf(fmaf(acc.x, inv, b4.x), 0.f);
    o.y = fmaxf(fmaf(acc.y, inv, b4.y), 0.f);
    o.z = fmaxf(fmaf(acc.z, inv, b4.z), 0.f);
    o.w = fmaxf(fmaf(acc.w, inv, b4.w), 0.f);
    *(float4*)(out + (size_t)d * 64 + r * 4) = o;
  }
}

extern "C" void kernel_launch(void* const* d_in, const int* in_sizes, int n_in,
                              void* d_out, int out_size, void* d_ws,
                              size_t ws_size, hipStream_t stream) {
  const float* x    = (const float*)d_in[0];
  const float* Wl   = (const float*)d_in[1];
  const float* bl   = (const float*)d_in[2];
  const float* Wr   = (const float*)d_in[3];
  const float* br   = (const float*)d_in[4];
  const float* att  = (const float*)d_in[5];
  const float* bias = (const float*)d_in[6];
  const int* eidx   = (const int*)d_in[7];
  float* out = (float*)d_out;

  const int N = in_sizes[0] / 128;   // 50000 (< 65536 required for packing)
  const int E = in_sizes[7] / 2;     // 800000
  const int NB = (N + 255) >> 8;     // 196 node buckets
  const int nbf = (E + CHUNK - 1) / CHUNK;  // 196 bfill blocks
  const int ntr = (N + 63) / 64;            // 782 transform blocks

  // ---- workspace layout ----
  short* xlb   = (short*)d_ws;                        // N*64 bf16
  float* xr    = (float*)(xlb + (size_t)N * 64);      // N*64 f32
  unsigned* pk = (unsigned*)(xr + (size_t)N * 64);    // NB*CAP u32
  unsigned short* csr = (unsigned short*)(pk + (size_t)NB * CAP);  // NB*CAP u16
  short* W2    = (short*)(csr + (size_t)NB * CAP);    // 128*128 bf16
  float* biasc = (float*)(W2 + 128 * 128);            // 128 f32
  int* bcur    = (int*)(biasc + 128);                 // NB
  int* rowlo   = bcur + NB;                           // N
  int* rowhi   = rowlo + N;                           // N

  k_prep<<<(128 * 128 + NB + 255) / 256, 256, 0, stream>>>(
      Wl, Wr, bl, br, W2, biasc, bcur, NB);
  k_tbf<<<nbf + ntr, 256, 0, stream>>>(x, W2, biasc, eidx, bcur, pk, xlb, xr,
                                       N, E, nbf);
  k_nfill<<<NB, 256, 0, stream>>>(pk, bcur, rowlo, rowhi, csr, N);
  k_node<<<(N + 3) / 4, 256, 0, stream>>>(rowlo, rowhi, csr, xlb, xr, att,
                                          bias, out, N);
}

// Round 11
// 78.093 us; speedup vs baseline: 1.4208x; 1.0508x over previous
//
#include <hip/hip_runtime.h>
#include <hip/hip_bf16.h>

#define NEG_SLOPE 0.2f
#define CAP 5120          // per-bucket capacity (avg 4096, ~16-sigma margin)
#define CHUNK 4096        // edges per workgroup in bfill path
#define LOG2E 1.4426950408889634f

typedef __attribute__((ext_vector_type(8))) short short8v;
typedef __attribute__((ext_vector_type(4))) short short4v;
typedef __attribute__((ext_vector_type(4))) float f32x4;

__device__ __forceinline__ short f2bf(float f) {
  __hip_bfloat16 b = __float2bfloat16(f);  // RNE
  return *reinterpret_cast<short*>(&b);
}
__device__ __forceinline__ float bf2f(short s) {
  return __uint_as_float(((unsigned)(unsigned short)s) << 16);
}

// 8-lane sum reduction in the VALU pipe via DPP: quad xor1, quad xor2, then
// row_half_mirror (0x141) crosses the two quads of the 8-lane half-row.
__device__ __forceinline__ float row_reduce8(float p) {
  p += __int_as_float(__builtin_amdgcn_update_dpp(
      0, __float_as_int(p), 0xB1, 0xF, 0xF, true));   // quad_perm [1,0,3,2]
  p += __int_as_float(__builtin_amdgcn_update_dpp(
      0, __float_as_int(p), 0x4E, 0xF, 0xF, true));   // quad_perm [2,3,0,1]
  p += __int_as_float(__builtin_amdgcn_update_dpp(
      0, __float_as_int(p), 0x141, 0xF, 0xF, true));  // row_half_mirror
  return p;
}

// K0: Wl||Wr -> W2[128ch][128k] bf16 (B-fragment layout), biasc, zero bcur.
__global__ __launch_bounds__(256) void k_prep(
    const float* __restrict__ Wl, const float* __restrict__ Wr,
    const float* __restrict__ bl, const float* __restrict__ br,
    short* __restrict__ W2, float* __restrict__ biasc,
    int* __restrict__ bcur, int nbk) {
  int idx = blockIdx.x * 256 + threadIdx.x;
  if (idx < 128 * 128) {
    int j = idx >> 7, k = idx & 127;
    float v = (j < 64) ? Wl[j * 128 + k] : Wr[(j - 64) * 128 + k];
    W2[idx] = f2bf(v);
  } else {
    int z = idx - 128 * 128;
    if (z < nbk) bcur[z] = 0;
  }
  if (idx < 128) biasc[idx] = (idx < 64) ? bl[idx] : br[idx - 64];
}

// K1 fused: blocks [0,nbf) = bucketed edge fill; blocks [nbf,..) = LDS-staged
// MFMA transform. Independent work co-scheduled; LDS unioned.
__global__ __launch_bounds__(256) void k_tbf(
    const float* __restrict__ x, const short* __restrict__ W2,
    const float* __restrict__ biasc, const int* __restrict__ eidx,
    int* __restrict__ bcur, unsigned* __restrict__ pk,
    short* __restrict__ xlb, float* __restrict__ xr, int nN, int E_,
    int nbf) {
  __shared__ union {
    struct { int hist[256]; int base[256]; } bf;
    short xs[64 * 136];
  } u;
  const int t = threadIdx.x;

  if (blockIdx.x < nbf) {
    // ---------------- bfill path ----------------
    u.bf.hist[t] = 0;
    __syncthreads();
    const int e0 = blockIdx.x * CHUNK + t * 16;
    unsigned mypk[16];
    int myrank[16];
    const bool valid = (e0 < E_);  // E_ % 16 == 0 -> all-or-nothing per thread
    if (valid) {
      const int4* ps = (const int4*)(eidx + e0);
      const int4* pd = (const int4*)(eidx + E_ + e0);
#pragma unroll
      for (int j = 0; j < 4; ++j) {
        int4 sv = ps[j];
        int4 dv = pd[j];
        int ss[4] = {sv.x, sv.y, sv.z, sv.w};
        int dd[4] = {dv.x, dv.y, dv.z, dv.w};
#pragma unroll
        for (int q = 0; q < 4; ++q) {
          unsigned p = ((unsigned)dd[q] << 16) | (unsigned)ss[q];
          mypk[j * 4 + q] = p;
          myrank[j * 4 + q] = atomicAdd(&u.bf.hist[dd[q] >> 8], 1);
        }
      }
    }
    __syncthreads();
    u.bf.base[t] = u.bf.hist[t] ? atomicAdd(&bcur[t], u.bf.hist[t]) : 0;
    __syncthreads();
    if (valid) {
#pragma unroll
      for (int j = 0; j < 16; ++j) {
        int b = mypk[j] >> 24;
        unsigned idx = (unsigned)(u.bf.base[b] + myrank[j]);
        if (idx < CAP) pk[(unsigned)b * CAP + idx] = mypk[j];
      }
    }
    return;
  }

  // ---------------- transform path ----------------
  const int n0 = (blockIdx.x - nbf) * 64;
#pragma unroll
  for (int i = 0; i < 8; ++i) {
    int f = (i * 256 + t) * 4;        // flat f32 index into 64x128 tile
    int node = f >> 7, k = f & 127;
    int gn = min(n0 + node, nN - 1);
    float4 v = *(const float4*)(x + (size_t)gn * 128 + k);
    short4v s4;
    s4[0] = f2bf(v.x); s4[1] = f2bf(v.y); s4[2] = f2bf(v.z); s4[3] = f2bf(v.w);
    *(short4v*)(u.xs + node * 136 + k) = s4;
  }
  __syncthreads();

  const int w = t >> 6;
  const int lane = t & 63;
  const int r = lane & 15;
  const int kb = lane >> 4;

  short8v bfr[2][4];
#pragma unroll
  for (int c = 0; c < 2; ++c) {
    const short* bp = W2 + (size_t)((w * 2 + c) * 16 + r) * 128 + kb * 8;
#pragma unroll
    for (int kk = 0; kk < 4; ++kk) bfr[c][kk] = *(const short8v*)(bp + kk * 32);
  }

  f32x4 acc[4][2];
#pragma unroll
  for (int nt = 0; nt < 4; ++nt)
#pragma unroll
    for (int c = 0; c < 2; ++c) acc[nt][c] = (f32x4){0.f, 0.f, 0.f, 0.f};

#pragma unroll
  for (int nt = 0; nt < 4; ++nt) {
    short8v afr[4];
#pragma unroll
    for (int kk = 0; kk < 4; ++kk)
      afr[kk] =
          *(const short8v*)(u.xs + (nt * 16 + r) * 136 + kb * 8 + kk * 32);
#pragma unroll
    for (int kk = 0; kk < 4; ++kk) {
      acc[nt][0] =
          __builtin_amdgcn_mfma_f32_16x16x32_bf16(afr[kk], bfr[0][kk],
                                                  acc[nt][0], 0, 0, 0);
      acc[nt][1] =
          __builtin_amdgcn_mfma_f32_16x16x32_bf16(afr[kk], bfr[1][kk],
                                                  acc[nt][1], 0, 0, 0);
    }
  }

#pragma unroll
  for (int c = 0; c < 2; ++c) {
    const int ch = (w * 2 + c) * 16 + r;
    const float bv = biasc[ch];
#pragma unroll
    for (int nt = 0; nt < 4; ++nt) {
#pragma unroll
      for (int i = 0; i < 4; ++i) {
        int node = n0 + nt * 16 + kb * 4 + i;
        if (node < nN) {
          float v = acc[nt][c][i] + bv;
          if (ch < 64) xlb[(size_t)node * 64 + ch] = f2bf(v);
          else         xr[(size_t)node * 64 + (ch - 64)] = v;
        }
      }
    }
  }
}

// K2: per-bucket finalize: node histogram -> scan -> rowlo/rowhi -> 2B csr.
__global__ __launch_bounds__(256) void k_nfill(
    const unsigned* __restrict__ pk, const int* __restrict__ bcur,
    int* __restrict__ rowlo, int* __restrict__ rowhi,
    unsigned short* __restrict__ csr, int nN) {
  __shared__ int hist[256];
  __shared__ int nbase[256];
  __shared__ int wsum[4];
  const int b = blockIdx.x;
  const int t = threadIdx.x;
  const int nb0 = b << 8;
  const int cnt = min(bcur[b], CAP);
  const unsigned gbase = (unsigned)b * CAP;
  hist[t] = 0;
  __syncthreads();
  for (int i = t; i < cnt; i += 256)
    atomicAdd(&hist[(pk[gbase + i] >> 16) & 255], 1);
  __syncthreads();
  const int lane = t & 63;
  const int wid = t >> 6;
  int v = hist[t];
  const int orig = v;
#pragma unroll
  for (int off = 1; off < 64; off <<= 1) {
    int uu = __shfl_up(v, off);
    if (lane >= off) v += uu;
  }
  if (lane == 63) wsum[wid] = v;
  __syncthreads();
  int add = 0;
  for (int ww = 0; ww < wid; ++ww) add += wsum[ww];
  const int excl = v - orig + add;
  nbase[t] = excl;
  if (nb0 + t < nN) {
    rowlo[nb0 + t] = (int)gbase + excl;
    rowhi[nb0 + t] = (int)gbase + excl + orig;
  }
  __syncthreads();
  hist[t] = 0;  // reuse as cursor
  __syncthreads();
  for (int i = t; i < cnt; i += 256) {
    unsigned p = pk[gbase + i];
    int dl = (p >> 16) & 255;
    int slot = nbase[dl] + atomicAdd(&hist[dl], 1);
    csr[gbase + slot] = (unsigned short)(p & 0xFFFFu);
  }
}

// K3: fused per-node online softmax. One wave per node; 8 subgroups x 8
// lanes; subgroup g walks edges lo+g, lo+g+8, ...; lane r owns channels
// 8r..8r+7. Defer-max: rescale only when a subgroup sees a new max
// (wave-uniform __any branch) — numerically identical, far fewer VALU ops.
__global__ __launch_bounds__(256) void k_node(
    const int* __restrict__ rowlo, const int* __restrict__ rowhi,
    const unsigned short* __restrict__ csr, const short* __restrict__ xlb,
    const float* __restrict__ xr, const float* __restrict__ att,
    const float* __restrict__ bias, float* __restrict__ out, int nN) {
  const int wid = (blockIdx.x * 256 + threadIdx.x) >> 6;  // node id
  if (wid >= nN) return;
  const int lane = threadIdx.x & 63;
  const int g = lane >> 3;          // subgroup 0..7
  const int r = lane & 7;           // channel block: ch 8r..8r+7
  const int d = wid;

  const float4 atA = *(const float4*)(att + r * 8);
  const float4 atB = *(const float4*)(att + r * 8 + 4);
  const float4 xrA = *(const float4*)(xr + (size_t)d * 64 + r * 8);
  const float4 xrB = *(const float4*)(xr + (size_t)d * 64 + r * 8 + 4);

  short8v sv = *(const short8v*)(xlb + (size_t)d * 64 + r * 8);
  const float s0 = bf2f(sv[0]), s1 = bf2f(sv[1]), s2 = bf2f(sv[2]),
              s3 = bf2f(sv[3]), s4 = bf2f(sv[4]), s5 = bf2f(sv[5]),
              s6 = bf2f(sv[6]), s7 = bf2f(sv[7]);

  // self-loop logit
  float hh, ps = 0.f;
  hh = s0 + xrA.x; hh = fmaxf(hh, NEG_SLOPE * hh); ps = fmaf(hh, atA.x, ps);
  hh = s1 + xrA.y; hh = fmaxf(hh, NEG_SLOPE * hh); ps = fmaf(hh, atA.y, ps);
  hh = s2 + xrA.z; hh = fmaxf(hh, NEG_SLOPE * hh); ps = fmaf(hh, atA.z, ps);
  hh = s3 + xrA.w; hh = fmaxf(hh, NEG_SLOPE * hh); ps = fmaf(hh, atA.w, ps);
  hh = s4 + xrB.x; hh = fmaxf(hh, NEG_SLOPE * hh); ps = fmaf(hh, atB.x, ps);
  hh = s5 + xrB.y; hh = fmaxf(hh, NEG_SLOPE * hh); ps = fmaf(hh, atB.y, ps);
  hh = s6 + xrB.z; hh = fmaxf(hh, NEG_SLOPE * hh); ps = fmaf(hh, atB.z, ps);
  hh = s7 + xrB.w; hh = fmaxf(hh, NEG_SLOPE * hh); ps = fmaf(hh, atB.w, ps);
  ps = row_reduce8(ps) * LOG2E;

  const bool g0 = (g == 0);
  float m = ps;                 // self logit = initial max (finite, exact)
  float ssum = g0 ? 1.f : 0.f;  // only subgroup 0 accounts the self edge
  float4 accA = g0 ? make_float4(s0, s1, s2, s3) : make_float4(0, 0, 0, 0);
  float4 accB = g0 ? make_float4(s4, s5, s6, s7) : make_float4(0, 0, 0, 0);

  const int lo = rowlo[d], hi = rowhi[d];
  const int nst = (hi - lo + 7) >> 3;

#define PROC(VREG, SIDX)                                                      \
  {                                                                           \
    const bool act = ((SIDX) < hi);                                           \
    const float f0 = bf2f(VREG[0]), f1 = bf2f(VREG[1]), f2 = bf2f(VREG[2]),   \
                f3 = bf2f(VREG[3]), f4 = bf2f(VREG[4]), f5 = bf2f(VREG[5]),   \
                f6 = bf2f(VREG[6]), f7 = bf2f(VREG[7]);                       \
    float p = 0.f;                                                            \
    hh = f0 + xrA.x; hh = fmaxf(hh, NEG_SLOPE * hh); p = fmaf(hh, atA.x, p);  \
    hh = f1 + xrA.y; hh = fmaxf(hh, NEG_SLOPE * hh); p = fmaf(hh, atA.y, p);  \
    hh = f2 + xrA.z; hh = fmaxf(hh, NEG_SLOPE * hh); p = fmaf(hh, atA.z, p);  \
    hh = f3 + xrA.w; hh = fmaxf(hh, NEG_SLOPE * hh); p = fmaf(hh, atA.w, p);  \
    hh = f4 + xrB.x; hh = fmaxf(hh, NEG_SLOPE * hh); p = fmaf(hh, atB.x, p);  \
    hh = f5 + xrB.y; hh = fmaxf(hh, NEG_SLOPE * hh); p = fmaf(hh, atB.y, p);  \
    hh = f6 + xrB.z; hh = fmaxf(hh, NEG_SLOPE * hh); p = fmaf(hh, atB.z, p);  \
    hh = f7 + xrB.w; hh = fmaxf(hh, NEG_SLOPE * hh); p = fmaf(hh, atB.w, p);  \
    p = row_reduce8(p);                                                       \
    const float pm = act ? p * LOG2E : -3.0e38f;                              \
    if (__any(pm > m)) {  /* rare: new max in some subgroup */                \
      const float nm = fmaxf(m, pm);                                          \
      const float sc = exp2f(m - nm);                                         \
      const float w = exp2f(pm - nm);                                         \
      ssum = fmaf(ssum, sc, w);                                               \
      accA.x = fmaf(accA.x, sc, w * f0);                                      \
      accA.y = fmaf(accA.y, sc, w * f1);                                      \
      accA.z = fmaf(accA.z, sc, w * f2);                                      \
      accA.w = fmaf(accA.w, sc, w * f3);                                      \
      accB.x = fmaf(accB.x, sc, w * f4);                                      \
      accB.y = fmaf(accB.y, sc, w * f5);                                      \
      accB.z = fmaf(accB.z, sc, w * f6);                                      \
      accB.w = fmaf(accB.w, sc, w * f7);                                      \
      m = nm;                                                                 \
    } else {              /* fast path: max unchanged, sc == 1 exactly */     \
      const float w = exp2f(pm - m);                                          \
      ssum += w;                                                              \
      accA.x = fmaf(w, f0, accA.x);                                           \
      accA.y = fmaf(w, f1, accA.y);                                           \
      accA.z = fmaf(w, f2, accA.z);                                           \
      accA.w = fmaf(w, f3, accA.w);                                           \
      accB.x = fmaf(w, f4, accB.x);                                           \
      accB.y = fmaf(w, f5, accB.y);                                           \
      accB.z = fmaf(w, f6, accB.z);                                           \
      accB.w = fmaf(w, f7, accB.w);                                           \
    }                                                                         \
  }

  int sA = lo + g, sB = sA + 8;
  short8v vA, vB;
  {
    int srcA = (sA < hi) ? (int)csr[sA] : d;
    vA = *(const short8v*)(xlb + (size_t)srcA * 64 + r * 8);
    int srcB = (sB < hi) ? (int)csr[sB] : d;
    vB = *(const short8v*)(xlb + (size_t)srcB * 64 + r * 8);
  }

  int tt = 0;
  for (; tt + 1 < nst; tt += 2) {
    PROC(vA, sA);
    if (tt + 2 < nst) {
      int sN = sA + 16;
      int srcN = (sN < hi) ? (int)csr[sN] : d;
      vA = *(const short8v*)(xlb + (size_t)srcN * 64 + r * 8);
    }
    PROC(vB, sB);
    if (tt + 3 < nst) {
      int sN = sB + 16;
      int srcN = (sN < hi) ? (int)csr[sN] : d;
      vB = *(const short8v*)(xlb + (size_t)srcN * 64 + r * 8);
    }
    sA += 16;
    sB += 16;
  }
  if (tt < nst) PROC(vA, sA);
#undef PROC

  // merge 8 subgroup partials (offsets 8, 16, 32)
#pragma unroll
  for (int off = 8; off <= 32; off <<= 1) {
    float mo = __shfl_xor(m, off);
    float so = __shfl_xor(ssum, off);
    float a0 = __shfl_xor(accA.x, off);
    float a1 = __shfl_xor(accA.y, off);
    float a2 = __shfl_xor(accA.z, off);
    float a3 = __shfl_xor(accA.w, off);
    float a4 = __shfl_xor(accB.x, off);
    float a5 = __shfl_xor(accB.y, off);
    float a6 = __shfl_xor(accB.z, off);
    float a7 = __shfl_xor(accB.w, off);
    float nm = fmaxf(m, mo);
    float sa = exp2f(m - nm);
    float sb2 = exp2f(mo - nm);
    ssum = ssum * sa + so * sb2;
    accA.x = accA.x * sa + a0 * sb2;
    accA.y = accA.y * sa + a1 * sb2;
    accA.z = accA.z * sa + a2 * sb2;
    accA.w = accA.w * sa + a3 * sb2;
    accB.x = accB.x * sa + a4 * sb2;
    accB.y = accB.y * sa + a5 * sb2;
    accB.z = accB.z * sa + a6 * sb2;
    accB.w = accB.w * sa + a7 * sb2;
    m = nm;
  }

  if (g == 0) {
    const float inv = 1.0f / ssum;
    const float4 bA = *(const float4*)(bias + r * 8);
    const float4 bB = *(const float4*)(bias + r * 8 + 4);
    float4 oA, oB;
    oA.x = fmaxf(fmaf(accA.x, inv, bA.x), 0.f);
    oA.y = fmaxf(fmaf(accA.y, inv, bA.y), 0.f);
    oA.z = fmaxf(fmaf(accA.z, inv, bA.z), 0.f);
    oA.w = fmaxf(fmaf(accA.w, inv, bA.w), 0.f);
    oB.x = fmaxf(fmaf(accB.x, inv, bB.x), 0.f);
    oB.y = fmaxf(fmaf(accB.y, inv, bB.y), 0.f);
    oB.z = fmaxf(fmaf(accB.z, inv, bB.z), 0.f);
    oB.w = fmaxf(fmaf(accB.w, inv, bB.w), 0.f);
    *(float4*)(out + (size_t)d * 64 + r * 8) = oA;
    *(float4*)(out + (size_t)d * 64 + r * 8 + 4) = oB;
  }
}

extern "C" void kernel_launch(void* const* d_in, const int* in_sizes, int n_in,
                              void* d_out, int out_size, void* d_ws,
                              size_t ws_size, hipStream_t stream) {
  const float* x    = (const float*)d_in[0];
  const float* Wl   = (const float*)d_in[1];
  const float* bl   = (const float*)d_in[2];
  const float* Wr   = (const float*)d_in[3];
  const float* br   = (const float*)d_in[4];
  const float* att  = (const float*)d_in[5];
  const float* bias = (const float*)d_in[6];
  const int* eidx   = (const int*)d_in[7];
  float* out = (float*)d_out;

  const int N = in_sizes[0] / 128;   // 50000 (< 65536 required for packing)
  const int E = in_sizes[7] / 2;     // 800000
  const int NB = (N + 255) >> 8;     // 196 node buckets
  const int nbf = (E + CHUNK - 1) / CHUNK;  // 196 bfill blocks
  const int ntr = (N + 63) / 64;            // 782 transform blocks

  // ---- workspace layout ----
  short* xlb   = (short*)d_ws;                        // N*64 bf16
  float* xr    = (float*)(xlb + (size_t)N * 64);      // N*64 f32
  unsigned* pk = (unsigned*)(xr + (size_t)N * 64);    // NB*CAP u32
  unsigned short* csr = (unsigned short*)(pk + (size_t)NB * CAP);  // NB*CAP u16
  short* W2    = (short*)(csr + (size_t)NB * CAP);    // 128*128 bf16
  float* biasc = (float*)(W2 + 128 * 128);            // 128 f32
  int* bcur    = (int*)(biasc + 128);                 // NB
  int* rowlo   = bcur + NB;                           // N
  int* rowhi   = rowlo + N;                           // N

  k_prep<<<(128 * 128 + NB + 255) / 256, 256, 0, stream>>>(
      Wl, Wr, bl, br, W2, biasc, bcur, NB);
  k_tbf<<<nbf + ntr, 256, 0, stream>>>(x, W2, biasc, eidx, bcur, pk, xlb, xr,
                                       N, E, nbf);
  k_nfill<<<NB, 256, 0, stream>>>(pk, bcur, rowlo, rowhi, csr, N);
  k_node<<<(N + 3) / 4, 256, 0, stream>>>(rowlo, rowhi, csr, xlb, xr, att,
                                          bias, out, N);
}

// Round 12
// 72.164 us; speedup vs baseline: 1.5375x; 1.0822x over previous
//
#include <hip/hip_runtime.h>
#include <hip/hip_bf16.h>

#define NEG_SLOPE 0.2f
#define CAP 5120          // per-bucket capacity (avg 4096, ~16-sigma margin)
#define CHUNK 4096        // edges per workgroup in bfill path
#define LOG2E 1.4426950408889634f

typedef __attribute__((ext_vector_type(8))) short short8v;
typedef __attribute__((ext_vector_type(4))) short short4v;
typedef __attribute__((ext_vector_type(4))) float f32x4;

__device__ __forceinline__ short f2bf(float f) {
  __hip_bfloat16 b = __float2bfloat16(f);  // RNE
  return *reinterpret_cast<short*>(&b);
}
__device__ __forceinline__ float bf2f(short s) {
  return __uint_as_float(((unsigned)(unsigned short)s) << 16);
}

// 8-lane sum reduction in the VALU pipe via DPP: quad xor1, quad xor2, then
// row_half_mirror (0x141) crosses the two quads of the 8-lane half-row.
__device__ __forceinline__ float row_reduce8(float p) {
  p += __int_as_float(__builtin_amdgcn_update_dpp(
      0, __float_as_int(p), 0xB1, 0xF, 0xF, true));   // quad_perm [1,0,3,2]
  p += __int_as_float(__builtin_amdgcn_update_dpp(
      0, __float_as_int(p), 0x4E, 0xF, 0xF, true));   // quad_perm [2,3,0,1]
  p += __int_as_float(__builtin_amdgcn_update_dpp(
      0, __float_as_int(p), 0x141, 0xF, 0xF, true));  // row_half_mirror
  return p;
}

// K0: Wl||Wr -> W2[128ch][128k] bf16 (B-fragment layout), biasc, zero bcur.
__global__ __launch_bounds__(256) void k_prep(
    const float* __restrict__ Wl, const float* __restrict__ Wr,
    const float* __restrict__ bl, const float* __restrict__ br,
    short* __restrict__ W2, float* __restrict__ biasc,
    int* __restrict__ bcur, int nbk) {
  int idx = blockIdx.x * 256 + threadIdx.x;
  if (idx < 128 * 128) {
    int j = idx >> 7, k = idx & 127;
    float v = (j < 64) ? Wl[j * 128 + k] : Wr[(j - 64) * 128 + k];
    W2[idx] = f2bf(v);
  } else {
    int z = idx - 128 * 128;
    if (z < nbk) bcur[z] = 0;
  }
  if (idx < 128) biasc[idx] = (idx < 64) ? bl[idx] : br[idx - 64];
}

// K1 fused: blocks [0,nbf) = bucketed edge fill; blocks [nbf,..) = LDS-staged
// MFMA transform. Independent work co-scheduled; LDS unioned.
__global__ __launch_bounds__(256) void k_tbf(
    const float* __restrict__ x, const short* __restrict__ W2,
    const float* __restrict__ biasc, const int* __restrict__ eidx,
    int* __restrict__ bcur, unsigned* __restrict__ pk,
    short* __restrict__ xlb, float* __restrict__ xr, int nN, int E_,
    int nbf) {
  __shared__ union {
    struct { int hist[256]; int base[256]; } bf;
    short xs[64 * 136];
  } u;
  const int t = threadIdx.x;

  if (blockIdx.x < nbf) {
    // ---------------- bfill path ----------------
    u.bf.hist[t] = 0;
    __syncthreads();
    const int e0 = blockIdx.x * CHUNK + t * 16;
    unsigned mypk[16];
    int myrank[16];
    const bool valid = (e0 < E_);  // E_ % 16 == 0 -> all-or-nothing per thread
    if (valid) {
      const int4* ps = (const int4*)(eidx + e0);
      const int4* pd = (const int4*)(eidx + E_ + e0);
#pragma unroll
      for (int j = 0; j < 4; ++j) {
        int4 sv = ps[j];
        int4 dv = pd[j];
        int ss[4] = {sv.x, sv.y, sv.z, sv.w};
        int dd[4] = {dv.x, dv.y, dv.z, dv.w};
#pragma unroll
        for (int q = 0; q < 4; ++q) {
          unsigned p = ((unsigned)dd[q] << 16) | (unsigned)ss[q];
          mypk[j * 4 + q] = p;
          myrank[j * 4 + q] = atomicAdd(&u.bf.hist[dd[q] >> 8], 1);
        }
      }
    }
    __syncthreads();
    u.bf.base[t] = u.bf.hist[t] ? atomicAdd(&bcur[t], u.bf.hist[t]) : 0;
    __syncthreads();
    if (valid) {
#pragma unroll
      for (int j = 0; j < 16; ++j) {
        int b = mypk[j] >> 24;
        unsigned idx = (unsigned)(u.bf.base[b] + myrank[j]);
        if (idx < CAP) pk[(unsigned)b * CAP + idx] = mypk[j];
      }
    }
    return;
  }

  // ---------------- transform path ----------------
  const int n0 = (blockIdx.x - nbf) * 64;
#pragma unroll
  for (int i = 0; i < 8; ++i) {
    int f = (i * 256 + t) * 4;        // flat f32 index into 64x128 tile
    int node = f >> 7, k = f & 127;
    int gn = min(n0 + node, nN - 1);
    float4 v = *(const float4*)(x + (size_t)gn * 128 + k);
    short4v s4;
    s4[0] = f2bf(v.x); s4[1] = f2bf(v.y); s4[2] = f2bf(v.z); s4[3] = f2bf(v.w);
    *(short4v*)(u.xs + node * 136 + k) = s4;
  }
  __syncthreads();

  const int w = t >> 6;
  const int lane = t & 63;
  const int r = lane & 15;
  const int kb = lane >> 4;

  short8v bfr[2][4];
#pragma unroll
  for (int c = 0; c < 2; ++c) {
    const short* bp = W2 + (size_t)((w * 2 + c) * 16 + r) * 128 + kb * 8;
#pragma unroll
    for (int kk = 0; kk < 4; ++kk) bfr[c][kk] = *(const short8v*)(bp + kk * 32);
  }

  f32x4 acc[4][2];
#pragma unroll
  for (int nt = 0; nt < 4; ++nt)
#pragma unroll
    for (int c = 0; c < 2; ++c) acc[nt][c] = (f32x4){0.f, 0.f, 0.f, 0.f};

#pragma unroll
  for (int nt = 0; nt < 4; ++nt) {
    short8v afr[4];
#pragma unroll
    for (int kk = 0; kk < 4; ++kk)
      afr[kk] =
          *(const short8v*)(u.xs + (nt * 16 + r) * 136 + kb * 8 + kk * 32);
#pragma unroll
    for (int kk = 0; kk < 4; ++kk) {
      acc[nt][0] =
          __builtin_amdgcn_mfma_f32_16x16x32_bf16(afr[kk], bfr[0][kk],
                                                  acc[nt][0], 0, 0, 0);
      acc[nt][1] =
          __builtin_amdgcn_mfma_f32_16x16x32_bf16(afr[kk], bfr[1][kk],
                                                  acc[nt][1], 0, 0, 0);
    }
  }

#pragma unroll
  for (int c = 0; c < 2; ++c) {
    const int ch = (w * 2 + c) * 16 + r;
    const float bv = biasc[ch];
#pragma unroll
    for (int nt = 0; nt < 4; ++nt) {
#pragma unroll
      for (int i = 0; i < 4; ++i) {
        int node = n0 + nt * 16 + kb * 4 + i;
        if (node < nN) {
          float v = acc[nt][c][i] + bv;
          if (ch < 64) xlb[(size_t)node * 64 + ch] = f2bf(v);
          else         xr[(size_t)node * 64 + (ch - 64)] = v;
        }
      }
    }
  }
}

// K2: per-bucket finalize: node histogram -> scan -> rowlo/rowhi -> 2B csr.
__global__ __launch_bounds__(256) void k_nfill(
    const unsigned* __restrict__ pk, const int* __restrict__ bcur,
    int* __restrict__ rowlo, int* __restrict__ rowhi,
    unsigned short* __restrict__ csr, int nN) {
  __shared__ int hist[256];
  __shared__ int nbase[256];
  __shared__ int wsum[4];
  const int b = blockIdx.x;
  const int t = threadIdx.x;
  const int nb0 = b << 8;
  const int cnt = min(bcur[b], CAP);
  const unsigned gbase = (unsigned)b * CAP;
  hist[t] = 0;
  __syncthreads();
  for (int i = t; i < cnt; i += 256)
    atomicAdd(&hist[(pk[gbase + i] >> 16) & 255], 1);
  __syncthreads();
  const int lane = t & 63;
  const int wid = t >> 6;
  int v = hist[t];
  const int orig = v;
#pragma unroll
  for (int off = 1; off < 64; off <<= 1) {
    int uu = __shfl_up(v, off);
    if (lane >= off) v += uu;
  }
  if (lane == 63) wsum[wid] = v;
  __syncthreads();
  int add = 0;
  for (int ww = 0; ww < wid; ++ww) add += wsum[ww];
  const int excl = v - orig + add;
  nbase[t] = excl;
  if (nb0 + t < nN) {
    rowlo[nb0 + t] = (int)gbase + excl;
    rowhi[nb0 + t] = (int)gbase + excl + orig;
  }
  __syncthreads();
  hist[t] = 0;  // reuse as cursor
  __syncthreads();
  for (int i = t; i < cnt; i += 256) {
    unsigned p = pk[gbase + i];
    int dl = (p >> 16) & 255;
    int slot = nbase[dl] + atomicAdd(&hist[dl], 1);
    csr[gbase + slot] = (unsigned short)(p & 0xFFFFu);
  }
}

// K3: fused per-node online softmax. TWO nodes per wave (half-wave each);
// per node: 4 subgroups x 8 lanes, lane r owns channels 8r..8r+7.
// m is kept UNIFORM within each half (half-wide max on rare new-max events)
// so the final merge is a pure 2-level sum with no exp/rescale.
__global__ __launch_bounds__(256) void k_node(
    const int* __restrict__ rowlo, const int* __restrict__ rowhi,
    const unsigned short* __restrict__ csr, const short* __restrict__ xlb,
    const float* __restrict__ xr, const float* __restrict__ att,
    const float* __restrict__ bias, float* __restrict__ out, int nN) {
  const int wvid = (blockIdx.x * 256 + threadIdx.x) >> 6;  // wave id
  const int lane = threadIdx.x & 63;
  const int h = lane >> 5;          // node half 0/1
  const int g = (lane >> 3) & 3;    // subgroup within half, 0..3
  const int r = lane & 7;           // channel block: ch 8r..8r+7
  int d = wvid * 2 + h;
  if (wvid * 2 >= nN) return;
  const bool live = (d < nN);
  d = min(d, nN - 1);

  const float4 atA = *(const float4*)(att + r * 8);
  const float4 atB = *(const float4*)(att + r * 8 + 4);
  const float4 xrA = *(const float4*)(xr + (size_t)d * 64 + r * 8);
  const float4 xrB = *(const float4*)(xr + (size_t)d * 64 + r * 8 + 4);

  short8v sv = *(const short8v*)(xlb + (size_t)d * 64 + r * 8);
  const float s0 = bf2f(sv[0]), s1 = bf2f(sv[1]), s2 = bf2f(sv[2]),
              s3 = bf2f(sv[3]), s4 = bf2f(sv[4]), s5 = bf2f(sv[5]),
              s6 = bf2f(sv[6]), s7 = bf2f(sv[7]);

  // self-loop logit (identical in all 4 subgroups of the half)
  float hh, ps = 0.f;
  hh = s0 + xrA.x; hh = fmaxf(hh, NEG_SLOPE * hh); ps = fmaf(hh, atA.x, ps);
  hh = s1 + xrA.y; hh = fmaxf(hh, NEG_SLOPE * hh); ps = fmaf(hh, atA.y, ps);
  hh = s2 + xrA.z; hh = fmaxf(hh, NEG_SLOPE * hh); ps = fmaf(hh, atA.z, ps);
  hh = s3 + xrA.w; hh = fmaxf(hh, NEG_SLOPE * hh); ps = fmaf(hh, atA.w, ps);
  hh = s4 + xrB.x; hh = fmaxf(hh, NEG_SLOPE * hh); ps = fmaf(hh, atB.x, ps);
  hh = s5 + xrB.y; hh = fmaxf(hh, NEG_SLOPE * hh); ps = fmaf(hh, atB.y, ps);
  hh = s6 + xrB.z; hh = fmaxf(hh, NEG_SLOPE * hh); ps = fmaf(hh, atB.z, ps);
  hh = s7 + xrB.w; hh = fmaxf(hh, NEG_SLOPE * hh); ps = fmaf(hh, atB.w, ps);
  ps = row_reduce8(ps) * LOG2E;

  const bool g0 = (g == 0);
  float m = ps;                 // uniform per half by construction
  float ssum = g0 ? 1.f : 0.f;
  float4 accA = g0 ? make_float4(s0, s1, s2, s3) : make_float4(0, 0, 0, 0);
  float4 accB = g0 ? make_float4(s4, s5, s6, s7) : make_float4(0, 0, 0, 0);

  const int lo = live ? rowlo[d] : 0;
  const int hi = live ? rowhi[d] : 0;
  const int nst = (hi - lo + 3) >> 2;   // rounds of 4 edges (one per subgroup)

#define PROC(VREG, SIDX)                                                      \
  {                                                                           \
    const bool act = ((SIDX) < hi);                                           \
    const float f0 = bf2f(VREG[0]), f1 = bf2f(VREG[1]), f2 = bf2f(VREG[2]),   \
                f3 = bf2f(VREG[3]), f4 = bf2f(VREG[4]), f5 = bf2f(VREG[5]),   \
                f6 = bf2f(VREG[6]), f7 = bf2f(VREG[7]);                       \
    float p = 0.f;                                                            \
    hh = f0 + xrA.x; hh = fmaxf(hh, NEG_SLOPE * hh); p = fmaf(hh, atA.x, p);  \
    hh = f1 + xrA.y; hh = fmaxf(hh, NEG_SLOPE * hh); p = fmaf(hh, atA.y, p);  \
    hh = f2 + xrA.z; hh = fmaxf(hh, NEG_SLOPE * hh); p = fmaf(hh, atA.z, p);  \
    hh = f3 + xrA.w; hh = fmaxf(hh, NEG_SLOPE * hh); p = fmaf(hh, atA.w, p);  \
    hh = f4 + xrB.x; hh = fmaxf(hh, NEG_SLOPE * hh); p = fmaf(hh, atB.x, p);  \
    hh = f5 + xrB.y; hh = fmaxf(hh, NEG_SLOPE * hh); p = fmaf(hh, atB.y, p);  \
    hh = f6 + xrB.z; hh = fmaxf(hh, NEG_SLOPE * hh); p = fmaf(hh, atB.w == atB.w ? atB.z : atB.z, p); \
    hh = f7 + xrB.w; hh = fmaxf(hh, NEG_SLOPE * hh); p = fmaf(hh, atB.w, p);  \
    p = row_reduce8(p);                                                       \
    const float pm = act ? p * LOG2E : -3.0e38f;                              \
    if (__any(pm > m)) {  /* rare: new max somewhere in the wave */           \
      float q = pm;                                                           \
      q = fmaxf(q, __shfl_xor(q, 8));                                         \
      q = fmaxf(q, __shfl_xor(q, 16));  /* half-wide max */                   \
      const float nm = fmaxf(m, q);     /* uniform per half */                \
      const float sc = exp2f(m - nm);                                         \
      const float w = exp2f(pm - nm);                                         \
      ssum = fmaf(ssum, sc, w);                                               \
      accA.x = fmaf(accA.x, sc, w * f0);                                      \
      accA.y = fmaf(accA.y, sc, w * f1);                                      \
      accA.z = fmaf(accA.z, sc, w * f2);                                      \
      accA.w = fmaf(accA.w, sc, w * f3);                                      \
      accB.x = fmaf(accB.x, sc, w * f4);                                      \
      accB.y = fmaf(accB.y, sc, w * f5);                                      \
      accB.z = fmaf(accB.z, sc, w * f6);                                      \
      accB.w = fmaf(accB.w, sc, w * f7);                                      \
      m = nm;                                                                 \
    } else {              /* fast path: sc == 1 exactly */                    \
      const float w = exp2f(pm - m);                                          \
      ssum += w;                                                              \
      accA.x = fmaf(w, f0, accA.x);                                           \
      accA.y = fmaf(w, f1, accA.y);                                           \
      accA.z = fmaf(w, f2, accA.z);                                           \
      accA.w = fmaf(w, f3, accA.w);                                           \
      accB.x = fmaf(w, f4, accB.x);                                           \
      accB.y = fmaf(w, f5, accB.y);                                           \
      accB.z = fmaf(w, f6, accB.z);                                           \
      accB.w = fmaf(w, f7, accB.w);                                           \
    }                                                                         \
  }

  int sA = lo + g, sB = sA + 4, sC = sA + 8;
  short8v vA, vB, vC;
  {
    int srcA = (sA < hi) ? (int)csr[sA] : d;
    vA = *(const short8v*)(xlb + (size_t)srcA * 64 + r * 8);
    int srcB = (sB < hi) ? (int)csr[sB] : d;
    vB = *(const short8v*)(xlb + (size_t)srcB * 64 + r * 8);
    int srcC = (sC < hi) ? (int)csr[sC] : d;
    vC = *(const short8v*)(xlb + (size_t)srcC * 64 + r * 8);
  }

  int tt = 0;
  for (; tt + 2 < nst; tt += 3) {
    PROC(vA, sA);
    if (tt + 3 < nst) {
      int sN = sA + 12;
      int srcN = (sN < hi) ? (int)csr[sN] : d;
      vA = *(const short8v*)(xlb + (size_t)srcN * 64 + r * 8);
    }
    PROC(vB, sB);
    if (tt + 4 < nst) {
      int sN = sB + 12;
      int srcN = (sN < hi) ? (int)csr[sN] : d;
      vB = *(const short8v*)(xlb + (size_t)srcN * 64 + r * 8);
    }
    PROC(vC, sC);
    if (tt + 5 < nst) {
      int sN = sC + 12;
      int srcN = (sN < hi) ? (int)csr[sN] : d;
      vC = *(const short8v*)(xlb + (size_t)srcN * 64 + r * 8);
    }
    sA += 12; sB += 12; sC += 12;
  }
  {
    const int rem = nst - tt;
    if (rem > 0) PROC(vA, sA);
    if (rem > 1) PROC(vB, sB);
  }
#undef PROC

  // merge 4 subgroup partials per half: pure sums (m uniform within half)
#pragma unroll
  for (int off = 8; off <= 16; off <<= 1) {
    ssum  += __shfl_xor(ssum, off);
    accA.x += __shfl_xor(accA.x, off);
    accA.y += __shfl_xor(accA.y, off);
    accA.z += __shfl_xor(accA.z, off);
    accA.w += __shfl_xor(accA.w, off);
    accB.x += __shfl_xor(accB.x, off);
    accB.y += __shfl_xor(accB.y, off);
    accB.z += __shfl_xor(accB.z, off);
    accB.w += __shfl_xor(accB.w, off);
  }

  if (g0 && live) {
    const float inv = 1.0f / ssum;
    const float4 bA = *(const float4*)(bias + r * 8);
    const float4 bB = *(const float4*)(bias + r * 8 + 4);
    float4 oA, oB;
    oA.x = fmaxf(fmaf(accA.x, inv, bA.x), 0.f);
    oA.y = fmaxf(fmaf(accA.y, inv, bA.y), 0.f);
    oA.z = fmaxf(fmaf(accA.z, inv, bA.z), 0.f);
    oA.w = fmaxf(fmaf(accA.w, inv, bA.w), 0.f);
    oB.x = fmaxf(fmaf(accB.x, inv, bB.x), 0.f);
    oB.y = fmaxf(fmaf(accB.y, inv, bB.y), 0.f);
    oB.z = fmaxf(fmaf(accB.z, inv, bB.z), 0.f);
    oB.w = fmaxf(fmaf(accB.w, inv, bB.w), 0.f);
    *(float4*)(out + (size_t)d * 64 + r * 8) = oA;
    *(float4*)(out + (size_t)d * 64 + r * 8 + 4) = oB;
  }
}

extern "C" void kernel_launch(void* const* d_in, const int* in_sizes, int n_in,
                              void* d_out, int out_size, void* d_ws,
                              size_t ws_size, hipStream_t stream) {
  const float* x    = (const float*)d_in[0];
  const float* Wl   = (const float*)d_in[1];
  const float* bl   = (const float*)d_in[2];
  const float* Wr   = (const float*)d_in[3];
  const float* br   = (const float*)d_in[4];
  const float* att  = (const float*)d_in[5];
  const float* bias = (const float*)d_in[6];
  const int* eidx   = (const int*)d_in[7];
  float* out = (float*)d_out;

  const int N = in_sizes[0] / 128;   // 50000 (< 65536 required for packing)
  const int E = in_sizes[7] / 2;     // 800000
  const int NB = (N + 255) >> 8;     // 196 node buckets
  const int nbf = (E + CHUNK - 1) / CHUNK;  // 196 bfill blocks
  const int ntr = (N + 63) / 64;            // 782 transform blocks

  // ---- workspace layout ----
  short* xlb   = (short*)d_ws;                        // N*64 bf16
  float* xr    = (float*)(xlb + (size_t)N * 64);      // N*64 f32
  unsigned* pk = (unsigned*)(xr + (size_t)N * 64);    // NB*CAP u32
  unsigned short* csr = (unsigned short*)(pk + (size_t)NB * CAP);  // NB*CAP u16
  short* W2    = (short*)(csr + (size_t)NB * CAP);    // 128*128 bf16
  float* biasc = (float*)(W2 + 128 * 128);            // 128 f32
  int* bcur    = (int*)(biasc + 128);                 // NB
  int* rowlo   = bcur + NB;                           // N
  int* rowhi   = rowlo + N;                           // N

  k_prep<<<(128 * 128 + NB + 255) / 256, 256, 0, stream>>>(
      Wl, Wr, bl, br, W2, biasc, bcur, NB);
  k_tbf<<<nbf + ntr, 256, 0, stream>>>(x, W2, biasc, eidx, bcur, pk, xlb, xr,
                                       N, E, nbf);
  k_nfill<<<NB, 256, 0, stream>>>(pk, bcur, rowlo, rowhi, csr, N);
  {
    int waves = (N + 1) / 2;
    k_node<<<(waves + 3) / 4, 256, 0, stream>>>(rowlo, rowhi, csr, xlb, xr,
                                                att, bias, out, N);
  }
}

// Round 13
// 69.293 us; speedup vs baseline: 1.6012x; 1.0414x over previous
//
#include <hip/hip_runtime.h>
#include <hip/hip_bf16.h>

#define NEG_SLOPE 0.2f
#define CAP 5120          // per-bucket capacity (avg 4096, ~16-sigma margin)
#define CHUNK 4096        // edges per workgroup in bfill path
#define LOG2E 1.4426950408889634f

typedef __attribute__((ext_vector_type(8))) short short8v;
typedef __attribute__((ext_vector_type(4))) short short4v;
typedef __attribute__((ext_vector_type(4))) float f32x4;
typedef _Float16 __attribute__((ext_vector_type(8))) h8;
typedef _Float16 __attribute__((ext_vector_type(2))) h2;

__device__ __forceinline__ short f2bf(float f) {
  __hip_bfloat16 b = __float2bfloat16(f);  // RNE
  return *reinterpret_cast<short*>(&b);
}

// f16x8 dot f16x8 accumulated into f32 via v_dot2_f32_f16 (4 instrs).
__device__ __forceinline__ float dot8f(h8 a, h8 b, float c) {
#if __has_builtin(__builtin_amdgcn_fdot2)
  c = __builtin_amdgcn_fdot2(__builtin_shufflevector(a, a, 0, 1),
                             __builtin_shufflevector(b, b, 0, 1), c, false);
  c = __builtin_amdgcn_fdot2(__builtin_shufflevector(a, a, 2, 3),
                             __builtin_shufflevector(b, b, 2, 3), c, false);
  c = __builtin_amdgcn_fdot2(__builtin_shufflevector(a, a, 4, 5),
                             __builtin_shufflevector(b, b, 4, 5), c, false);
  c = __builtin_amdgcn_fdot2(__builtin_shufflevector(a, a, 6, 7),
                             __builtin_shufflevector(b, b, 6, 7), c, false);
#else
#pragma unroll
  for (int i = 0; i < 8; ++i) c += (float)a[i] * (float)b[i];
#endif
  return c;
}

// packed leakyrelu: max(h, 0.2h) elementwise (v_pk_mul + v_pk_max)
__device__ __forceinline__ h8 leaky8(h8 hs) {
  h8 hl = hs * (_Float16)NEG_SLOPE;
  return __builtin_elementwise_max(hs, hl);
}

__device__ __forceinline__ h8 shfl_xor_h8(h8 v, int off) {
  int4 i = *(int4*)&v;
  i.x = __shfl_xor(i.x, off);
  i.y = __shfl_xor(i.y, off);
  i.z = __shfl_xor(i.z, off);
  i.w = __shfl_xor(i.w, off);
  return *(h8*)&i;
}

// 8-lane sum reduction in the VALU pipe via DPP.
__device__ __forceinline__ float row_reduce8(float p) {
  p += __int_as_float(__builtin_amdgcn_update_dpp(
      0, __float_as_int(p), 0xB1, 0xF, 0xF, true));   // quad_perm [1,0,3,2]
  p += __int_as_float(__builtin_amdgcn_update_dpp(
      0, __float_as_int(p), 0x4E, 0xF, 0xF, true));   // quad_perm [2,3,0,1]
  p += __int_as_float(__builtin_amdgcn_update_dpp(
      0, __float_as_int(p), 0x141, 0xF, 0xF, true));  // row_half_mirror
  return p;
}

// K0: Wl||Wr -> W2[128ch][128k] bf16 (B-fragment layout), biasc, zero bcur.
__global__ __launch_bounds__(256) void k_prep(
    const float* __restrict__ Wl, const float* __restrict__ Wr,
    const float* __restrict__ bl, const float* __restrict__ br,
    short* __restrict__ W2, float* __restrict__ biasc,
    int* __restrict__ bcur, int nbk) {
  int idx = blockIdx.x * 256 + threadIdx.x;
  if (idx < 128 * 128) {
    int j = idx >> 7, k = idx & 127;
    float v = (j < 64) ? Wl[j * 128 + k] : Wr[(j - 64) * 128 + k];
    W2[idx] = f2bf(v);
  } else {
    int z = idx - 128 * 128;
    if (z < nbk) bcur[z] = 0;
  }
  if (idx < 128) biasc[idx] = (idx < 64) ? bl[idx] : br[idx - 64];
}

// K1 fused: blocks [0,nbf) = bucketed edge fill; blocks [nbf,..) = LDS-staged
// MFMA transform (outputs f16 xlh / xrh).
__global__ __launch_bounds__(256) void k_tbf(
    const float* __restrict__ x, const short* __restrict__ W2,
    const float* __restrict__ biasc, const int* __restrict__ eidx,
    int* __restrict__ bcur, unsigned* __restrict__ pk,
    _Float16* __restrict__ xlh, _Float16* __restrict__ xrh, int nN, int E_,
    int nbf) {
  __shared__ union {
    struct { int hist[256]; int base[256]; } bf;
    short xs[64 * 136];
  } u;
  const int t = threadIdx.x;

  if (blockIdx.x < nbf) {
    // ---------------- bfill path ----------------
    u.bf.hist[t] = 0;
    __syncthreads();
    const int e0 = blockIdx.x * CHUNK + t * 16;
    unsigned mypk[16];
    int myrank[16];
    const bool valid = (e0 < E_);  // E_ % 16 == 0 -> all-or-nothing per thread
    if (valid) {
      const int4* ps = (const int4*)(eidx + e0);
      const int4* pd = (const int4*)(eidx + E_ + e0);
#pragma unroll
      for (int j = 0; j < 4; ++j) {
        int4 sv = ps[j];
        int4 dv = pd[j];
        int ss[4] = {sv.x, sv.y, sv.z, sv.w};
        int dd[4] = {dv.x, dv.y, dv.z, dv.w};
#pragma unroll
        for (int q = 0; q < 4; ++q) {
          unsigned p = ((unsigned)dd[q] << 16) | (unsigned)ss[q];
          mypk[j * 4 + q] = p;
          myrank[j * 4 + q] = atomicAdd(&u.bf.hist[dd[q] >> 8], 1);
        }
      }
    }
    __syncthreads();
    u.bf.base[t] = u.bf.hist[t] ? atomicAdd(&bcur[t], u.bf.hist[t]) : 0;
    __syncthreads();
    if (valid) {
#pragma unroll
      for (int j = 0; j < 16; ++j) {
        int b = mypk[j] >> 24;
        unsigned idx = (unsigned)(u.bf.base[b] + myrank[j]);
        if (idx < CAP) pk[(unsigned)b * CAP + idx] = mypk[j];
      }
    }
    return;
  }

  // ---------------- transform path ----------------
  const int n0 = (blockIdx.x - nbf) * 64;
#pragma unroll
  for (int i = 0; i < 8; ++i) {
    int f = (i * 256 + t) * 4;        // flat f32 index into 64x128 tile
    int node = f >> 7, k = f & 127;
    int gn = min(n0 + node, nN - 1);
    float4 v = *(const float4*)(x + (size_t)gn * 128 + k);
    short4v s4;
    s4[0] = f2bf(v.x); s4[1] = f2bf(v.y); s4[2] = f2bf(v.z); s4[3] = f2bf(v.w);
    *(short4v*)(u.xs + node * 136 + k) = s4;
  }
  __syncthreads();

  const int w = t >> 6;
  const int lane = t & 63;
  const int r = lane & 15;
  const int kb = lane >> 4;

  short8v bfr[2][4];
#pragma unroll
  for (int c = 0; c < 2; ++c) {
    const short* bp = W2 + (size_t)((w * 2 + c) * 16 + r) * 128 + kb * 8;
#pragma unroll
    for (int kk = 0; kk < 4; ++kk) bfr[c][kk] = *(const short8v*)(bp + kk * 32);
  }

  f32x4 acc[4][2];
#pragma unroll
  for (int nt = 0; nt < 4; ++nt)
#pragma unroll
    for (int c = 0; c < 2; ++c) acc[nt][c] = (f32x4){0.f, 0.f, 0.f, 0.f};

#pragma unroll
  for (int nt = 0; nt < 4; ++nt) {
    short8v afr[4];
#pragma unroll
    for (int kk = 0; kk < 4; ++kk)
      afr[kk] =
          *(const short8v*)(u.xs + (nt * 16 + r) * 136 + kb * 8 + kk * 32);
#pragma unroll
    for (int kk = 0; kk < 4; ++kk) {
      acc[nt][0] =
          __builtin_amdgcn_mfma_f32_16x16x32_bf16(afr[kk], bfr[0][kk],
                                                  acc[nt][0], 0, 0, 0);
      acc[nt][1] =
          __builtin_amdgcn_mfma_f32_16x16x32_bf16(afr[kk], bfr[1][kk],
                                                  acc[nt][1], 0, 0, 0);
    }
  }

#pragma unroll
  for (int c = 0; c < 2; ++c) {
    const int ch = (w * 2 + c) * 16 + r;
    const float bv = biasc[ch];
#pragma unroll
    for (int nt = 0; nt < 4; ++nt) {
#pragma unroll
      for (int i = 0; i < 4; ++i) {
        int node = n0 + nt * 16 + kb * 4 + i;
        if (node < nN) {
          float v = acc[nt][c][i] + bv;
          if (ch < 64) xlh[(size_t)node * 64 + ch] = (_Float16)v;
          else         xrh[(size_t)node * 64 + (ch - 64)] = (_Float16)v;
        }
      }
    }
  }
}

// K2: per-bucket finalize: node histogram -> scan -> rowlo/rowhi -> 2B csr.
__global__ __launch_bounds__(256) void k_nfill(
    const unsigned* __restrict__ pk, const int* __restrict__ bcur,
    int* __restrict__ rowlo, int* __restrict__ rowhi,
    unsigned short* __restrict__ csr, int nN) {
  __shared__ int hist[256];
  __shared__ int nbase[256];
  __shared__ int wsum[4];
  const int b = blockIdx.x;
  const int t = threadIdx.x;
  const int nb0 = b << 8;
  const int cnt = min(bcur[b], CAP);
  const unsigned gbase = (unsigned)b * CAP;
  hist[t] = 0;
  __syncthreads();
  for (int i = t; i < cnt; i += 256)
    atomicAdd(&hist[(pk[gbase + i] >> 16) & 255], 1);
  __syncthreads();
  const int lane = t & 63;
  const int wid = t >> 6;
  int v = hist[t];
  const int orig = v;
#pragma unroll
  for (int off = 1; off < 64; off <<= 1) {
    int uu = __shfl_up(v, off);
    if (lane >= off) v += uu;
  }
  if (lane == 63) wsum[wid] = v;
  __syncthreads();
  int add = 0;
  for (int ww = 0; ww < wid; ++ww) add += wsum[ww];
  const int excl = v - orig + add;
  nbase[t] = excl;
  if (nb0 + t < nN) {
    rowlo[nb0 + t] = (int)gbase + excl;
    rowhi[nb0 + t] = (int)gbase + excl + orig;
  }
  __syncthreads();
  hist[t] = 0;  // reuse as cursor
  __syncthreads();
  for (int i = t; i < cnt; i += 256) {
    unsigned p = pk[gbase + i];
    int dl = (p >> 16) & 255;
    int slot = nbase[dl] + atomicAdd(&hist[dl], 1);
    csr[gbase + slot] = (unsigned short)(p & 0xFFFFu);
  }
}

// K3: fused per-node online softmax, f16 packed datapath. TWO nodes per wave
// (half-wave each); per node 4 subgroups x 8 lanes; lane r owns ch 8r..8r+7.
// m uniform per half (half-wide max on rare new-max) -> final merge is a pure
// sum. Defer-max fast path: sc == 1 exactly.
__global__ __launch_bounds__(256) void k_node(
    const int* __restrict__ rowlo, const int* __restrict__ rowhi,
    const unsigned short* __restrict__ csr, const _Float16* __restrict__ xlh,
    const _Float16* __restrict__ xrh, const float* __restrict__ att,
    const float* __restrict__ bias, float* __restrict__ out, int nN) {
  const int wvid = (blockIdx.x * 256 + threadIdx.x) >> 6;  // wave id
  const int lane = threadIdx.x & 63;
  const int h = lane >> 5;          // node half 0/1
  const int g = (lane >> 3) & 3;    // subgroup within half, 0..3
  const int r = lane & 7;           // channel block: ch 8r..8r+7
  int d = wvid * 2 + h;
  if (wvid * 2 >= nN) return;
  const bool live = (d < nN);
  d = min(d, nN - 1);

  h8 at8;
#pragma unroll
  for (int i = 0; i < 8; ++i) at8[i] = (_Float16)att[r * 8 + i];

  const h8 xr8 = *(const h8*)(xrh + (size_t)d * 64 + r * 8);
  const h8 sv8 = *(const h8*)(xlh + (size_t)d * 64 + r * 8);

  // self-loop logit (identical across the half's 4 subgroups)
  float ps = dot8f(leaky8(sv8 + xr8), at8, 0.f);
  ps = row_reduce8(ps) * LOG2E;

  const bool g0 = (g == 0);
  float m = ps;                 // uniform per half by construction
  float ssum = g0 ? 1.f : 0.f;
  h8 acc = g0 ? sv8 : (h8){0, 0, 0, 0, 0, 0, 0, 0};

  const int lo = live ? rowlo[d] : 0;
  const int hi = live ? rowhi[d] : 0;
  const int nst = (hi - lo + 3) >> 2;   // rounds of 4 edges per node

#define PROC(VREG, SIDX)                                                      \
  {                                                                           \
    const bool act = ((SIDX) < hi);                                           \
    float p = dot8f(leaky8(VREG + xr8), at8, 0.f);                            \
    p = row_reduce8(p);                                                       \
    const float pm = act ? p * LOG2E : -3.0e38f;                              \
    if (__any(pm > m)) {  /* rare: new max somewhere in the wave */           \
      float q = pm;                                                           \
      q = fmaxf(q, __shfl_xor(q, 8));                                         \
      q = fmaxf(q, __shfl_xor(q, 16));  /* half-wide max */                   \
      const float nm = fmaxf(m, q);     /* uniform per half */                \
      const float sc = exp2f(m - nm);                                         \
      const float w = exp2f(pm - nm);                                         \
      ssum = fmaf(ssum, sc, w);                                               \
      acc = acc * (_Float16)sc + VREG * (_Float16)w;                          \
      m = nm;                                                                 \
    } else {              /* fast path: sc == 1 exactly */                    \
      const float w = exp2f(pm - m);                                          \
      ssum += w;                                                              \
      acc += VREG * (_Float16)w;                                              \
    }                                                                         \
  }

  int sA = lo + g, sB = sA + 4, sC = sA + 8;
  h8 vA, vB, vC;
  {
    int srcA = (sA < hi) ? (int)csr[sA] : d;
    vA = *(const h8*)(xlh + (size_t)srcA * 64 + r * 8);
    int srcB = (sB < hi) ? (int)csr[sB] : d;
    vB = *(const h8*)(xlh + (size_t)srcB * 64 + r * 8);
    int srcC = (sC < hi) ? (int)csr[sC] : d;
    vC = *(const h8*)(xlh + (size_t)srcC * 64 + r * 8);
  }

  int tt = 0;
  for (; tt + 2 < nst; tt += 3) {
    PROC(vA, sA);
    if (tt + 3 < nst) {
      int sN = sA + 12;
      int srcN = (sN < hi) ? (int)csr[sN] : d;
      vA = *(const h8*)(xlh + (size_t)srcN * 64 + r * 8);
    }
    PROC(vB, sB);
    if (tt + 4 < nst) {
      int sN = sB + 12;
      int srcN = (sN < hi) ? (int)csr[sN] : d;
      vB = *(const h8*)(xlh + (size_t)srcN * 64 + r * 8);
    }
    PROC(vC, sC);
    if (tt + 5 < nst) {
      int sN = sC + 12;
      int srcN = (sN < hi) ? (int)csr[sN] : d;
      vC = *(const h8*)(xlh + (size_t)srcN * 64 + r * 8);
    }
    sA += 12; sB += 12; sC += 12;
  }
  {
    const int rem = nst - tt;
    if (rem > 0) PROC(vA, sA);
    if (rem > 1) PROC(vB, sB);
  }
#undef PROC

  // merge 4 subgroup partials per half: pure sums (m uniform within half)
#pragma unroll
  for (int off = 8; off <= 16; off <<= 1) {
    ssum += __shfl_xor(ssum, off);
    acc += shfl_xor_h8(acc, off);
  }

  if (g0 && live) {
    const float inv = 1.0f / ssum;
    const float4 bA = *(const float4*)(bias + r * 8);
    const float4 bB = *(const float4*)(bias + r * 8 + 4);
    float4 oA, oB;
    oA.x = fmaxf(fmaf((float)acc[0], inv, bA.x), 0.f);
    oA.y = fmaxf(fmaf((float)acc[1], inv, bA.y), 0.f);
    oA.z = fmaxf(fmaf((float)acc[2], inv, bA.z), 0.f);
    oA.w = fmaxf(fmaf((float)acc[3], inv, bA.w), 0.f);
    oB.x = fmaxf(fmaf((float)acc[4], inv, bB.x), 0.f);
    oB.y = fmaxf(fmaf((float)acc[5], inv, bB.y), 0.f);
    oB.z = fmaxf(fmaf((float)acc[6], inv, bB.z), 0.f);
    oB.w = fmaxf(fmaf((float)acc[7], inv, bB.w), 0.f);
    *(float4*)(out + (size_t)d * 64 + r * 8) = oA;
    *(float4*)(out + (size_t)d * 64 + r * 8 + 4) = oB;
  }
}

extern "C" void kernel_launch(void* const* d_in, const int* in_sizes, int n_in,
                              void* d_out, int out_size, void* d_ws,
                              size_t ws_size, hipStream_t stream) {
  const float* x    = (const float*)d_in[0];
  const float* Wl   = (const float*)d_in[1];
  const float* bl   = (const float*)d_in[2];
  const float* Wr   = (const float*)d_in[3];
  const float* br   = (const float*)d_in[4];
  const float* att  = (const float*)d_in[5];
  const float* bias = (const float*)d_in[6];
  const int* eidx   = (const int*)d_in[7];
  float* out = (float*)d_out;

  const int N = in_sizes[0] / 128;   // 50000 (< 65536 required for packing)
  const int E = in_sizes[7] / 2;     // 800000
  const int NB = (N + 255) >> 8;     // 196 node buckets
  const int nbf = (E + CHUNK - 1) / CHUNK;  // 196 bfill blocks
  const int ntr = (N + 63) / 64;            // 782 transform blocks

  // ---- workspace layout ----
  _Float16* xlh = (_Float16*)d_ws;                    // N*64 f16
  _Float16* xrh = xlh + (size_t)N * 64;               // N*64 f16
  unsigned* pk = (unsigned*)(xrh + (size_t)N * 64);   // NB*CAP u32
  unsigned short* csr = (unsigned short*)(pk + (size_t)NB * CAP);  // NB*CAP u16
  short* W2    = (short*)(csr + (size_t)NB * CAP);    // 128*128 bf16
  float* biasc = (float*)(W2 + 128 * 128);            // 128 f32
  int* bcur    = (int*)(biasc + 128);                 // NB
  int* rowlo   = bcur + NB;                           // N
  int* rowhi   = rowlo + N;                           // N

  k_prep<<<(128 * 128 + NB + 255) / 256, 256, 0, stream>>>(
      Wl, Wr, bl, br, W2, biasc, bcur, NB);
  k_tbf<<<nbf + ntr, 256, 0, stream>>>(x, W2, biasc, eidx, bcur, pk, xlh, xrh,
                                       N, E, nbf);
  k_nfill<<<NB, 256, 0, stream>>>(pk, bcur, rowlo, rowhi, csr, N);
  {
    int waves = (N + 1) / 2;
    k_node<<<(waves + 3) / 4, 256, 0, stream>>>(rowlo, rowhi, csr, xlh, xrh,
                                                att, bias, out, N);
  }
}